// Round 20
// baseline (683.215 us; speedup 1.0000x reference)
//
#include <hip/hip_runtime.h>

typedef unsigned short u16;
typedef unsigned int   u32;
typedef __attribute__((ext_vector_type(8))) __bf16 bf16x8;
typedef __attribute__((ext_vector_type(4))) float  f32x4;

#define BQ   8
#define SQ   4096
#define NHQ  16
#define HIDD 1024
#define TOKN 32768

__device__ __forceinline__ u16 f2bf(float f){
  u32 u = __builtin_bit_cast(u32, f);
  u += 0x7fffu + ((u >> 16) & 1u);
  return (u16)(u >> 16);
}
__device__ __forceinline__ float bf2f(u16 h){
  return __builtin_bit_cast(float, (u32)h << 16);
}
__device__ __forceinline__ void gl16(const void* g, void* l){
  __builtin_amdgcn_global_load_lds((const __attribute__((address_space(1))) void*)g,
                                   (__attribute__((address_space(3))) void*)l, 16, 0, 0);
}
#define MFMA(a,b,c) __builtin_amdgcn_mfma_f32_16x16x32_bf16((a),(b),(c),0,0,0)

// ---------------- merged weight prep: casts (Wk,Wv,Wo) + Wq'=gamma*Wq (+cq,dq) ----------------
__global__ __launch_bounds__(256) void k_prep(const float* __restrict__ wk,
    const float* __restrict__ wv, const float* __restrict__ wo,
    const float* __restrict__ Wq, const float* __restrict__ gam,
    const float* __restrict__ bet, const float* __restrict__ bq,
    u16* __restrict__ okv, u16* __restrict__ oo,
    u16* __restrict__ wqb, float* __restrict__ cq, float* __restrict__ dq){
  const int t = threadIdx.x;
  if (blockIdx.x < 3072){
    const int sel = blockIdx.x >> 10;
    const int i = ((blockIdx.x & 1023) << 8) + t;
    const float* in = (sel == 0) ? wk : (sel == 1) ? wv : wo;
    u16* o = (sel == 0) ? okv : (sel == 1) ? (okv + 1024 * 1024) : oo;
    float4 v = ((const float4*)in)[i];
    ushort4 r;
    r.x = f2bf(v.x); r.y = f2bf(v.y); r.z = f2bf(v.z); r.w = f2bf(v.w);
    ((ushort4*)o)[i] = r;
  } else {
    const int j = blockIdx.x - 3072;
    const float4 wvq = ((const float4*)(Wq + (size_t)j * 1024))[t];
    const float4 gv = ((const float4*)gam)[t];
    const float4 bv = ((const float4*)bet)[t];
    ushort4 r;
    r.x = f2bf(wvq.x * gv.x); r.y = f2bf(wvq.y * gv.y);
    r.z = f2bf(wvq.z * gv.z); r.w = f2bf(wvq.w * gv.w);
    ((ushort4*)(wqb + (size_t)j * 1024))[t] = r;
    float sc = bf2f(r.x) + bf2f(r.y) + bf2f(r.z) + bf2f(r.w);   // rounded, matches GEMM
    float sd = wvq.x * bv.x + wvq.y * bv.y + wvq.z * bv.z + wvq.w * bv.w;
    #pragma unroll
    for (int o = 1; o < 64; o <<= 1){ sc += __shfl_xor(sc, o); sd += __shfl_xor(sd, o); }
    __shared__ float sm[8];
    const int lane = t & 63, wid = t >> 6;
    if (lane == 0){ sm[wid] = sc; sm[wid + 4] = sd; }
    __syncthreads();
    if (t == 0){
      cq[j] = sm[0] + sm[1] + sm[2] + sm[3];
      dq[j] = sm[4] + sm[5] + sm[6] + sm[7] + bq[j];
    }
  }
}

// ---------------- LayerNorm stats + cast x ----------------
__global__ __launch_bounds__(256) void k_ln(const float* __restrict__ x,
    u16* __restrict__ xbf, float* __restrict__ mur, float* __restrict__ rsd){
  const int row = blockIdx.x, t = threadIdx.x;
  const float4 v = ((const float4*)(x + (size_t)row * HIDD))[t];
  float s  = v.x + v.y + v.z + v.w;
  float ss = v.x*v.x + v.y*v.y + v.z*v.z + v.w*v.w;
  #pragma unroll
  for (int o = 1; o < 64; o <<= 1){ s += __shfl_xor(s, o); ss += __shfl_xor(ss, o); }
  __shared__ float sm[8];
  const int lane = t & 63, wid = t >> 6;
  if (lane == 0){ sm[wid] = s; sm[wid + 4] = ss; }
  __syncthreads();
  s  = sm[0] + sm[1] + sm[2] + sm[3];
  ss = sm[4] + sm[5] + sm[6] + sm[7];
  const float mu   = s * (1.f / 1024.f);
  const float var  = ss * (1.f / 1024.f) - mu * mu;
  const float rstd = rsqrtf(var + 1e-12f);
  if (t == 0){ mur[row] = mu * rstd; rsd[row] = rstd; }
  ushort4 xo;
  xo.x = f2bf(v.x); xo.y = f2bf(v.y); xo.z = f2bf(v.z); xo.w = f2bf(v.w);
  ((ushort4*)(xbf + (size_t)row * HIDD))[t] = xo;
}

// ---------------- 256x256 NT GEMM (r9/r12/r15 structure; SPLIT=1 = 4-phase variant) ----------------
// C[M,N] = A[M,1024]*W[N,1024]^T + bias (+resid bf16). 8 waves (2Mx4N), BK=64, counted
// vmcnt(4), gl_lds staging w/ source swizzle g=(lane&7)^(lane>>3), read granule ^ (lane&7).
// V-half (voutT && n0>=nsplit) stores transposed to vT via [32][66] cep (64B burst/lane).
// Q path (cq set): LN-linearized epilogue v = rstd[row]*acc - murstd[row]*cq[col] + dq[col].
// RES epilogue: fp32 out = acc + bias + bf16-residual (uint4 reads).
struct GP {
  const u16* A; const u16* W; const float* b1; const float* b2;
  int nsplit, lgNB, LDC, nblk; u16* outb; u16* voutT;
  const float* cq; const float* dq; const float* mur; const float* rsd;
};

template<int RES, int SPLIT>
__global__ __launch_bounds__(512, 2) void k_gemm256(GP p0, GP p1, int seg0,
    const u16* __restrict__ residb, float* __restrict__ outf){
  __shared__ union {
    u16 st[2][2][16384];     // [buf][A/B][row*64 + gp*8], 256x64 bf16 each = 128 KiB
    float cep[8][1056];      // per-wave [16][66] f32
    float cep2[8][2112];     // per-wave [32][66] f32 (V transposed path)
  } sm;

  const GP& p = (blockIdx.x < seg0) ? p0 : p1;
  const int bseg = (blockIdx.x < seg0) ? blockIdx.x : blockIdx.x - seg0;
  const u16* __restrict__ A = p.A;
  const u16* __restrict__ W = p.W;
  const int lgNB = p.lgNB, LDC = p.LDC;

  const int wg = ((bseg & 7) * (p.nblk >> 3)) + (bseg >> 3);   // XCD-chunked (nblk % 8 == 0)
  const int m0 = (wg >> lgNB) << 8;
  const int n0 = (wg & ((1 << lgNB) - 1)) << 8;

  const int t = threadIdx.x, lane = t & 63, wid = t >> 6;
  const int ln15 = lane & 15, hi = lane >> 4;
  const int wr = wid >> 2, wc = wid & 3;
  const int lg = lane & 7, lr = lane >> 3;

  auto stage = [&](int buf, int op, const u16* __restrict__ src, int rowoff, int kt){
    #pragma unroll
    for (int i = 0; i < 4; i++){
      const int cb  = ((i << 3) + wid) << 6;
      const int row = (cb >> 3) + lr;
      const int g   = lg ^ lr;
      gl16(src + (size_t)(rowoff + row) * HIDD + (kt << 6) + (g << 3),
           &sm.st[buf][op][cb << 3]);
    }
  };
  auto stageH = [&](int buf, int op, const u16* __restrict__ src, int rowoff, int kt, int half){
    #pragma unroll
    for (int i2 = 0; i2 < 2; i2++){
      const int i = (half << 1) + i2;
      const int cb  = ((i << 3) + wid) << 6;
      const int row = (cb >> 3) + lr;
      const int g   = lg ^ lr;
      gl16(src + (size_t)(rowoff + row) * HIDD + (kt << 6) + (g << 3),
           &sm.st[buf][op][cb << 3]);
    }
  };
  #define RD_A(c,m,ks) (*(const bf16x8*)&sm.st[c][0][(((wr << 7) + ((m) << 4) + ln15) << 6) + \
      (((((ks) << 2) + hi) ^ (lane & 7)) << 3)])
  #define RD_B(c,n,ks) (*(const bf16x8*)&sm.st[c][1][(((wc << 6) + ((n) << 4) + ln15) << 6) + \
      (((((ks) << 2) + hi) ^ (lane & 7)) << 3)])
  #define BARF do { asm volatile("" ::: "memory"); __builtin_amdgcn_s_barrier(); asm volatile("" ::: "memory"); } while(0)

  f32x4 acc[8][4] = {};

  stage(0, 0, A, m0, 0);
  stage(0, 1, W, n0, 0);
  stage(1, 1, W, n0, 1);
  asm volatile("s_waitcnt vmcnt(4)" ::: "memory");
  BARF;

  const int NT = HIDD / 64;
  if constexpr (SPLIT == 0){
    for (int kt = 0; kt < NT; ++kt){
      const int c = kt & 1;
      bf16x8 af[4][2], bq[4][2];
      #pragma unroll
      for (int m = 0; m < 4; m++){ af[m][0] = RD_A(c, m, 0); af[m][1] = RD_A(c, m, 1); }
      #pragma unroll
      for (int n = 0; n < 4; n++){ bq[n][0] = RD_B(c, n, 0); bq[n][1] = RD_B(c, n, 1); }
      const int ka = kt + 1 < NT ? kt + 1 : NT - 1;
      stage(c ^ 1, 0, A, m0, ka);
      __builtin_amdgcn_s_setprio(1);
      #pragma unroll
      for (int m = 0; m < 4; m++)
        #pragma unroll
        for (int n = 0; n < 4; n++){
          acc[m][n] = MFMA(af[m][0], bq[n][0], acc[m][n]);
          acc[m][n] = MFMA(af[m][1], bq[n][1], acc[m][n]);
        }
      __builtin_amdgcn_s_setprio(0);
      BARF;
      #pragma unroll
      for (int m = 0; m < 4; m++){ af[m][0] = RD_A(c, m + 4, 0); af[m][1] = RD_A(c, m + 4, 1); }
      const int kb = kt + 2 < NT ? kt + 2 : NT - 1;
      stage(c, 1, W, n0, kb);
      __builtin_amdgcn_s_setprio(1);
      #pragma unroll
      for (int m = 0; m < 4; m++)
        #pragma unroll
        for (int n = 0; n < 4; n++){
          acc[m + 4][n] = MFMA(af[m][0], bq[n][0], acc[m + 4][n]);
          acc[m + 4][n] = MFMA(af[m][1], bq[n][1], acc[m + 4][n]);
        }
      __builtin_amdgcn_s_setprio(0);
      asm volatile("s_waitcnt vmcnt(4)" ::: "memory");
      BARF;
    }
  } else {
    for (int kt = 0; kt < NT; ++kt){
      const int c = kt & 1;
      const int ka  = kt + 1 < NT ? kt + 1 : NT - 1;
      const int kb2 = kt + 2 < NT ? kt + 2 : NT - 1;
      bf16x8 af[2][2], bq[4][2];
      af[0][0] = RD_A(c, 0, 0); af[0][1] = RD_A(c, 0, 1);
      af[1][0] = RD_A(c, 1, 0); af[1][1] = RD_A(c, 1, 1);
      #pragma unroll
      for (int n = 0; n < 4; n++){ bq[n][0] = RD_B(c, n, 0); bq[n][1] = RD_B(c, n, 1); }
      stageH(c ^ 1, 0, A, m0, ka, 0);
      __builtin_amdgcn_s_setprio(1);
      #pragma unroll
      for (int m = 0; m < 2; m++)
        #pragma unroll
        for (int n = 0; n < 4; n++){
          acc[m][n] = MFMA(af[m][0], bq[n][0], acc[m][n]);
          acc[m][n] = MFMA(af[m][1], bq[n][1], acc[m][n]);
        }
      __builtin_amdgcn_s_setprio(0);
      BARF;
      af[0][0] = RD_A(c, 2, 0); af[0][1] = RD_A(c, 2, 1);
      af[1][0] = RD_A(c, 3, 0); af[1][1] = RD_A(c, 3, 1);
      stageH(c ^ 1, 0, A, m0, ka, 1);
      __builtin_amdgcn_s_setprio(1);
      #pragma unroll
      for (int m = 0; m < 2; m++)
        #pragma unroll
        for (int n = 0; n < 4; n++){
          acc[m + 2][n] = MFMA(af[m][0], bq[n][0], acc[m + 2][n]);
          acc[m + 2][n] = MFMA(af[m][1], bq[n][1], acc[m + 2][n]);
        }
      __builtin_amdgcn_s_setprio(0);
      BARF;
      af[0][0] = RD_A(c, 4, 0); af[0][1] = RD_A(c, 4, 1);
      af[1][0] = RD_A(c, 5, 0); af[1][1] = RD_A(c, 5, 1);
      stageH(c, 1, W, n0, kb2, 0);
      __builtin_amdgcn_s_setprio(1);
      #pragma unroll
      for (int m = 0; m < 2; m++)
        #pragma unroll
        for (int n = 0; n < 4; n++){
          acc[m + 4][n] = MFMA(af[m][0], bq[n][0], acc[m + 4][n]);
          acc[m + 4][n] = MFMA(af[m][1], bq[n][1], acc[m + 4][n]);
        }
      __builtin_amdgcn_s_setprio(0);
      BARF;
      af[0][0] = RD_A(c, 6, 0); af[0][1] = RD_A(c, 6, 1);
      af[1][0] = RD_A(c, 7, 0); af[1][1] = RD_A(c, 7, 1);
      stageH(c, 1, W, n0, kb2, 1);
      __builtin_amdgcn_s_setprio(1);
      #pragma unroll
      for (int m = 0; m < 2; m++)
        #pragma unroll
        for (int n = 0; n < 4; n++){
          acc[m + 6][n] = MFMA(af[m][0], bq[n][0], acc[m + 6][n]);
          acc[m + 6][n] = MFMA(af[m][1], bq[n][1], acc[m + 6][n]);
        }
      __builtin_amdgcn_s_setprio(0);
      asm volatile("s_waitcnt vmcnt(4)" ::: "memory");
      BARF;
    }
  }
  #undef RD_A
  #undef RD_B

  asm volatile("s_waitcnt vmcnt(0)" ::: "memory");
  BARF;

  const float* bp = (n0 < p.nsplit) ? p.b1 : (p.b2 - p.nsplit);
  float bn[4];
  #pragma unroll
  for (int n = 0; n < 4; n++) bn[n] = bp[n0 + (wc << 6) + (n << 4) + ln15];

  if constexpr (RES){
    float* cw = &sm.cep[wid][0];
    const int rr = lane >> 3, cb8 = (lane & 7) << 3;
    #pragma unroll
    for (int m = 0; m < 8; m++){
      #pragma unroll
      for (int n = 0; n < 4; n++)
        #pragma unroll
        for (int r = 0; r < 4; r++)
          cw[((hi << 2) + r) * 66 + (n << 4) + ln15] = acc[m][n][r] + bn[n];
      #pragma unroll
      for (int j = 0; j < 2; j++){
        const int row = (j << 3) + rr;
        const size_t gr = (size_t)(m0 + (wr << 7) + (m << 4) + row);
        const size_t gidx = gr * LDC + n0 + (wc << 6) + cb8;
        const size_t ridx = gr * HIDD + n0 + (wc << 6) + cb8;
        const uint4 rv = *(const uint4*)&residb[ridx];
        const u32 rr4[4] = {rv.x, rv.y, rv.z, rv.w};
        float4 o0, o1;
        o0.x = cw[row * 66 + cb8 + 0] + bf2f((u16)(rr4[0] & 0xffff));
        o0.y = cw[row * 66 + cb8 + 1] + bf2f((u16)(rr4[0] >> 16));
        o0.z = cw[row * 66 + cb8 + 2] + bf2f((u16)(rr4[1] & 0xffff));
        o0.w = cw[row * 66 + cb8 + 3] + bf2f((u16)(rr4[1] >> 16));
        o1.x = cw[row * 66 + cb8 + 4] + bf2f((u16)(rr4[2] & 0xffff));
        o1.y = cw[row * 66 + cb8 + 5] + bf2f((u16)(rr4[2] >> 16));
        o1.z = cw[row * 66 + cb8 + 6] + bf2f((u16)(rr4[3] & 0xffff));
        o1.w = cw[row * 66 + cb8 + 7] + bf2f((u16)(rr4[3] >> 16));
        *(float4*)&outf[gidx]     = o0;
        *(float4*)&outf[gidx + 4] = o1;
      }
    }
  } else if (p.voutT != nullptr && n0 >= p.nsplit){
    // V half: store transposed to vT[((b*16+h)*64 + d)*SQ + s], 64B burst per lane
    float* cw = &sm.cep2[wid][0];                 // [32][66]
    const int e0 = n0 - p.nsplit + (wc << 6);
    const int hh = e0 >> 6;
    u16* vt = p.voutT;
    #pragma unroll
    for (int mp = 0; mp < 4; mp++){
      #pragma unroll
      for (int mh = 0; mh < 2; mh++){
        const int m = (mp << 1) + mh;
        #pragma unroll
        for (int n = 0; n < 4; n++)
          #pragma unroll
          for (int r = 0; r < 4; r++)
            cw[((mh << 4) + (hi << 2) + r) * 66 + (n << 4) + ln15] = acc[m][n][r] + bn[n];
      }
      const int rg0 = m0 + (wr << 7) + (mp << 5);
      const int bb = rg0 >> 12, s0 = rg0 & 4095;
      u16* dst = vt + (((size_t)(bb << 4) + hh) * 64 + lane) * SQ + s0;
      #pragma unroll
      for (int j = 0; j < 4; j++){
        u32 ro[4];
        #pragma unroll
        for (int q = 0; q < 4; q++){
          float v0 = cw[((j << 3) + 2 * q    ) * 66 + lane];
          float v1 = cw[((j << 3) + 2 * q + 1) * 66 + lane];
          ro[q] = (u32)f2bf(v0) | ((u32)f2bf(v1) << 16);
        }
        uint4 o; o.x = ro[0]; o.y = ro[1]; o.z = ro[2]; o.w = ro[3];
        *(uint4*)&dst[j << 3] = o;
      }
    }
  } else {
    float* cw = &sm.cep[wid][0];
    const int rr = lane >> 3, cb8 = (lane & 7) << 3;
    u16* outb = p.outb;
    if (p.cq != nullptr){
      // Q path: LN-linearized correction, then bf16 row-major store
      float cqn[4], dqn[4];
      #pragma unroll
      for (int n = 0; n < 4; n++){
        const int col = n0 + (wc << 6) + (n << 4) + ln15;
        cqn[n] = p.cq[col]; dqn[n] = p.dq[col];
      }
      #pragma unroll
      for (int m = 0; m < 8; m++){
        #pragma unroll
        for (int r = 0; r < 4; r++){
          const int grow = m0 + (wr << 7) + (m << 4) + (hi << 2) + r;
          const float mu = p.mur[grow], rs = p.rsd[grow];
          #pragma unroll
          for (int n = 0; n < 4; n++)
            cw[((hi << 2) + r) * 66 + (n << 4) + ln15] = rs * acc[m][n][r] - mu * cqn[n] + dqn[n];
        }
        #pragma unroll
        for (int j = 0; j < 2; j++){
          const int row = (j << 3) + rr;
          u32 ro[4];
          #pragma unroll
          for (int pq = 0; pq < 4; pq++){
            float v0 = cw[row * 66 + cb8 + 2 * pq];
            float v1 = cw[row * 66 + cb8 + 2 * pq + 1];
            ro[pq] = (u32)f2bf(v0) | ((u32)f2bf(v1) << 16);
          }
          uint4 o; o.x = ro[0]; o.y = ro[1]; o.z = ro[2]; o.w = ro[3];
          *(uint4*)&outb[(size_t)(m0 + (wr << 7) + (m << 4) + row) * LDC
                         + n0 + (wc << 6) + cb8] = o;
        }
      }
    } else {
      #pragma unroll
      for (int m = 0; m < 8; m++){
        #pragma unroll
        for (int n = 0; n < 4; n++)
          #pragma unroll
          for (int r = 0; r < 4; r++)
            cw[((hi << 2) + r) * 66 + (n << 4) + ln15] = acc[m][n][r] + bn[n];
        #pragma unroll
        for (int j = 0; j < 2; j++){
          const int row = (j << 3) + rr;
          u32 ro[4];
          #pragma unroll
          for (int pq = 0; pq < 4; pq++){
            float v0 = cw[row * 66 + cb8 + 2 * pq];
            float v1 = cw[row * 66 + cb8 + 2 * pq + 1];
            ro[pq] = (u32)f2bf(v0) | ((u32)f2bf(v1) << 16);
          }
          uint4 o; o.x = ro[0]; o.y = ro[1]; o.z = ro[2]; o.w = ro[3];
          *(uint4*)&outb[(size_t)(m0 + (wr << 7) + (m << 4) + row) * LDC
                         + n0 + (wc << 6) + cb8] = o;
        }
      }
    }
  }
  #undef BARF
}

// ---------------- transpose K: kb [B,S,1024] -> ekT [B,H,64,S] with elu+L2norm ----------------
__global__ __launch_bounds__(256) void k_transposeK(const u16* __restrict__ kb,
                                                    u16* __restrict__ ekT){
  __shared__ float tile[64][65];
  __shared__ float pr[64][4];
  __shared__ float rn[64];
  const int sb = blockIdx.x << 6, h = blockIdx.y, b = blockIdx.z;
  const int t = threadIdx.x;
  {
    const int tok = t >> 2, q = t & 3;
    const u16* src = kb + (size_t)(b * SQ + sb + tok) * 1024 + (h << 6) + (q << 4);
    uint4 u0 = *(const uint4*)src;
    uint4 u1 = *(const uint4*)(src + 8);
    u32 uu[8] = {u0.x, u0.y, u0.z, u0.w, u1.x, u1.y, u1.z, u1.w};
    float ss = 0.f;
    #pragma unroll
    for (int i = 0; i < 8; i++){
      float f0 = bf2f((u16)(uu[i] & 0xffff));
      float f1 = bf2f((u16)(uu[i] >> 16));
      f0 = f0 > 0.f ? f0 : expm1f(f0);
      f1 = f1 > 0.f ? f1 : expm1f(f1);
      ss += f0 * f0 + f1 * f1;
      tile[tok][(q << 4) + 2*i]     = f0;
      tile[tok][(q << 4) + 2*i + 1] = f1;
    }
    pr[tok][q] = ss;
  }
  __syncthreads();
  if (t < 64) rn[t] = rsqrtf(pr[t][0] + pr[t][1] + pr[t][2] + pr[t][3]);
  __syncthreads();
  const int d = t >> 2, sq2 = (t & 3) << 4;
  u16* dst = ekT + ((size_t)(b * NHQ + h) * 64 + d) * SQ + sb + sq2;
  u32 ro[8];
  #pragma unroll
  for (int i = 0; i < 8; i++){
    float v0 = tile[sq2 + 2*i][d]     * rn[sq2 + 2*i];
    float v1 = tile[sq2 + 2*i + 1][d] * rn[sq2 + 2*i + 1];
    ro[i] = (u32)f2bf(v0) | ((u32)f2bf(v1) << 16);
  }
  uint4 o0; o0.x = ro[0]; o0.y = ro[1]; o0.z = ro[2]; o0.w = ro[3];
  uint4 o1; o1.x = ro[4]; o1.y = ro[5]; o1.z = ro[6]; o1.w = ro[7];
  *(uint4*)dst = o0;
  *(uint4*)(dst + 8) = o1;
}

// ---------------- kv split-K x4: per (b,h,qtr) partial[e][d] = sum_{s in qtr} v[s][e] ek[s][d] ----------------
// 512 blocks (4 per bh) -> 2 blocks/CU. f32 partials reduced inside k_ctx's B-staging.
__global__ __launch_bounds__(256) void k_kv(const u16* __restrict__ vT, const u16* __restrict__ ekT,
                                            float* __restrict__ kvP){
  const int qtr = blockIdx.x & 3, bh = blockIdx.x >> 2;
  const u16* Av = vT  + (size_t)bh * 64 * SQ;
  const u16* Bk = ekT + (size_t)bh * 64 * SQ;
  const int lane = threadIdx.x & 63, wid = threadIdx.x >> 6;
  const int ln15 = lane & 15, hi = lane >> 4;
  f32x4 acc[4][4] = {};
  const int kb = (qtr << 10) + (wid << 8);
  for (int ks = 0; ks < 8; ++ks){
    const int k0 = kb + (ks << 5) + (hi << 3);
    bf16x8 af[4], bfr[4];
    #pragma unroll
    for (int m = 0; m < 4; m++) af[m]  = *(const bf16x8*)(Av + (size_t)((m << 4) + ln15) * SQ + k0);
    #pragma unroll
    for (int n = 0; n < 4; n++) bfr[n] = *(const bf16x8*)(Bk + (size_t)((n << 4) + ln15) * SQ + k0);
    #pragma unroll
    for (int m = 0; m < 4; m++)
      #pragma unroll
      for (int n = 0; n < 4; n++)
        acc[m][n] = MFMA(af[m], bfr[n], acc[m][n]);
  }
  __shared__ float red[64][64];
  for (int w = 0; w < 4; ++w){
    if (wid == w){
      #pragma unroll
      for (int m = 0; m < 4; m++)
        #pragma unroll
        for (int n = 0; n < 4; n++)
          #pragma unroll
          for (int r = 0; r < 4; r++){
            int row = (m << 4) + (hi << 2) + r;
            int col = (n << 4) + ln15;
            if (w == 0) red[row][col] = acc[m][n][r];
            else        red[row][col] += acc[m][n][r];
          }
    }
    __syncthreads();
  }
  float* dst = kvP + (size_t)blockIdx.x * 4096;   // blockIdx = bh*4 + qtr
  const int tt = threadIdx.x;
  #pragma unroll
  for (int i = 0; i < 16; i++){
    int idx = tt * 16 + i;
    dst[idx] = red[idx >> 6][idx & 63];
  }
}

// ---------------- ctx (+ fused elu/L2norm on q; B from 4 f32 kv partials) ----------------
__global__ __launch_bounds__(256) void k_ctx(const u16* __restrict__ q, const float* __restrict__ kvP,
                                             u16* __restrict__ ctx){
  __shared__ u16 Alds[1024 * 8];
  __shared__ u16 Blds[512 * 8];
  __shared__ float prn[128][2];
  const int sb = blockIdx.x << 7;
  const int h = blockIdx.y, b = blockIdx.z;
  const int bh = (b << 4) + h;
  const int t = threadIdx.x, lane = t & 63, wid = t >> 6;
  const int ln15 = lane & 15, hi = lane >> 4;
  {
    uint4 va[4]; uint4 vb[2];
    #pragma unroll
    for (int i = 0; i < 4; i++){
      int c = (wid << 6) + (i << 8) + lane;
      int g = c >> 7, row = c & 127;
      va[i] = *(const uint4*)(q + (size_t)(b * SQ + sb + row) * HIDD + (h << 6) + g * 8);
    }
    // B: reduce 4 f32 split-K partials (L2-resident), x0.125, cvt bf16
    const float* pp = kvP + ((size_t)bh << 14);   // 4 partials x 4096
    #pragma unroll
    for (int i = 0; i < 2; i++){
      int c = (wid << 6) + (i << 8) + lane;
      int g = c >> 6, row = c & 63;
      const int eidx = (row << 6) + (g << 3);
      float s[8] = {0.f, 0.f, 0.f, 0.f, 0.f, 0.f, 0.f, 0.f};
      #pragma unroll
      for (int qq = 0; qq < 4; qq++){
        const float4 a = *(const float4*)&pp[(qq << 12) + eidx];
        const float4 bq2 = *(const float4*)&pp[(qq << 12) + eidx + 4];
        s[0] += a.x; s[1] += a.y; s[2] += a.z; s[3] += a.w;
        s[4] += bq2.x; s[5] += bq2.y; s[6] += bq2.z; s[7] += bq2.w;
      }
      u32 ro[4];
      #pragma unroll
      for (int j = 0; j < 4; j++)
        ro[j] = (u32)f2bf(s[2*j] * 0.125f) | ((u32)f2bf(s[2*j+1] * 0.125f) << 16);
      uint4 o; o.x = ro[0]; o.y = ro[1]; o.z = ro[2]; o.w = ro[3];
      vb[i] = o;
    }
    #pragma unroll
    for (int i = 0; i < 4; i++)
      *(uint4*)&Alds[((wid << 6) + (i << 8) + lane) * 8] = va[i];
    #pragma unroll
    for (int i = 0; i < 2; i++)
      *(uint4*)&Blds[((wid << 6) + (i << 8) + lane) * 8] = vb[i];
  }
  __syncthreads();
  {
    const int row = t & 127, half = t >> 7;
    float vals[4][8]; float ss = 0.f;
    #pragma unroll
    for (int g4 = 0; g4 < 4; g4++){
      const int g = (half << 2) + g4;
      uint4 u = *(const uint4*)&Alds[((g << 7) + row) * 8];
      u32 uu[4] = {u.x, u.y, u.z, u.w};
      #pragma unroll
      for (int i = 0; i < 4; i++){
        float f0 = bf2f((u16)(uu[i] & 0xffff));
        float f1 = bf2f((u16)(uu[i] >> 16));
        f0 = f0 > 0.f ? f0 : expm1f(f0);
        f1 = f1 > 0.f ? f1 : expm1f(f1);
        vals[g4][2*i] = f0; vals[g4][2*i+1] = f1;
        ss += f0 * f0 + f1 * f1;
      }
    }
    prn[row][half] = ss;
    __syncthreads();
    const float rn = rsqrtf(prn[row][0] + prn[row][1]);
    #pragma unroll
    for (int g4 = 0; g4 < 4; g4++){
      const int g = (half << 2) + g4;
      u32 ro[4];
      #pragma unroll
      for (int i = 0; i < 4; i++)
        ro[i] = (u32)f2bf(vals[g4][2*i] * rn) | ((u32)f2bf(vals[g4][2*i+1] * rn) << 16);
      uint4 o; o.x = ro[0]; o.y = ro[1]; o.z = ro[2]; o.w = ro[3];
      *(uint4*)&Alds[((g << 7) + row) * 8] = o;
    }
  }
  __syncthreads();
  f32x4 acc[2][4] = {};
  #pragma unroll
  for (int k2 = 0; k2 < 2; k2++){
    const int g = (k2 << 2) + hi;
    bf16x8 af[2], bfr[4];
    #pragma unroll
    for (int m = 0; m < 2; m++) af[m]  = *(const bf16x8*)&Alds[((g << 7) + (wid << 5) + (m << 4) + ln15) * 8];
    #pragma unroll
    for (int n = 0; n < 4; n++) bfr[n] = *(const bf16x8*)&Blds[((g << 6) + (n << 4) + ln15) * 8];
    #pragma unroll
    for (int m = 0; m < 2; m++)
      #pragma unroll
      for (int n = 0; n < 4; n++)
        acc[m][n] = MFMA(af[m], bfr[n], acc[m][n]);
  }
  #pragma unroll
  for (int m = 0; m < 2; m++)
    #pragma unroll
    for (int n = 0; n < 4; n++)
      #pragma unroll
      for (int r = 0; r < 4; r++){
        int srow = sb + (wid << 5) + (m << 4) + (hi << 2) + r;
        int col  = (n << 4) + ln15;
        ctx[(size_t)(b * SQ + srow) * HIDD + (h << 6) + col] = f2bf(acc[m][n][r]);
      }
}

extern "C" void kernel_launch(void* const* d_in, const int* in_sizes, int n_in,
                              void* d_out, int out_size, void* d_ws, size_t ws_size,
                              hipStream_t stream){
  const float* x   = (const float*)d_in[0];
  const float* lng = (const float*)d_in[2];
  const float* lnb = (const float*)d_in[3];
  const float* Wq  = (const float*)d_in[4];
  const float* bq  = (const float*)d_in[5];
  const float* Wk  = (const float*)d_in[6];
  const float* bk  = (const float*)d_in[7];
  const float* Wv  = (const float*)d_in[8];
  const float* bv  = (const float*)d_in[9];
  const float* Wo  = (const float*)d_in[10];
  const float* bo  = (const float*)d_in[11];
  float* out = (float*)d_out;

  char* w = (char*)d_ws;
  const size_t MB = 1ull << 20;
  u16* wqb  = (u16*)(w + 0   * MB);   // 2 MiB: Wq' = gamma*Wq (bf16)
  u16* wkvb = (u16*)(w + 2   * MB);   // 4 MiB: [Wk; Wv] stacked [2048][1024]
  u16* wob  = (u16*)(w + 6   * MB);   // 2 MiB
  u16* xbf  = (u16*)(w + 8   * MB);   // 64 MiB (live through out-GEMM: bf16 residual)
  u16* xnbf = (u16*)(w + 72  * MB);   // 64 MiB (ekT scratch)
  u16* qb   = (u16*)(w + 136 * MB);   // 64 MiB (raw q; elu+norm fused into k_ctx)
  u16* kb   = (u16*)(w + 200 * MB);   // 64 MiB (raw k, row-major)
  u16* vT   = (u16*)(w + 264 * MB);   // 64 MiB (v transposed [B,H,64,S], direct from GEMM)
  float* murstd = (float*)(w + 330 * MB);  // 128 KiB
  float* rstdv  = (float*)(w + 331 * MB);  // 128 KiB
  float* cqv    = (float*)(w + 332 * MB);  // 4 KiB
  float* dqv    = (float*)(w + 333 * MB);  // 4 KiB
  float* kvP    = (float*)(w + 336 * MB);  // 8 MiB f32 split-K partials (128 bh x 4 x 4096)
  // aliases (stream-ordered lifetimes)
  u16* ekT = xnbf;
  u16* ctx = kb;    // kb dead after k_transposeK

  k_prep<<<4096, 256, 0, stream>>>(Wk, Wv, Wo, Wq, lng, lnb, bq, wkvb, wob, wqb, cqv, dqv);
  k_ln<<<TOKN, 256, 0, stream>>>(x, xbf, murstd, rstdv);

  // merged Q + KV GEMM (2-phase): Q blocks [0,512) with A=xbf + LN-linearized epilogue;
  // KV blocks [512,1536): K half -> kb row-major; V half -> vT transposed
  GP pq  = { xbf, wqb,  bq, bq, 1 << 30, 2, 1024, 512,  qb, nullptr, cqv, dqv, murstd, rstdv };
  GP pkv = { xbf, wkvb, bk, bv, 1024,    3, 1024, 1024, kb, vT,      nullptr, nullptr, nullptr, nullptr };
  k_gemm256<0, 0><<<1536, 512, 0, stream>>>(pq, pkv, 512, nullptr, nullptr);

  k_transposeK<<<dim3(64, 16, 8), 256, 0, stream>>>(kb, ekT);
  k_kv<<<512, 256, 0, stream>>>(vT, ekT, kvP);
  k_ctx<<<dim3(32, 16, 8), 256, 0, stream>>>(qb, kvP, ctx);

  // out GEMM (4-phase): bf16 residual from xbf + fp32 out
  GP po = { ctx, wob, bo, bo, 1 << 30, 2, 1024, 512, nullptr, nullptr,
            nullptr, nullptr, nullptr, nullptr };
  k_gemm256<1, 1><<<512, 512, 0, stream>>>(po, po, 512, xbf, out);

  (void)in_sizes; (void)n_in; (void)out_size; (void)ws_size;
}

// Round 21
// 658.170 us; speedup vs baseline: 1.0381x; 1.0381x over previous
//
#include <hip/hip_runtime.h>

typedef unsigned short u16;
typedef unsigned int   u32;
typedef __attribute__((ext_vector_type(8))) __bf16 bf16x8;
typedef __attribute__((ext_vector_type(4))) float  f32x4;

#define BQ   8
#define SQ   4096
#define NHQ  16
#define HIDD 1024
#define TOKN 32768

__device__ __forceinline__ u16 f2bf(float f){
  u32 u = __builtin_bit_cast(u32, f);
  u += 0x7fffu + ((u >> 16) & 1u);
  return (u16)(u >> 16);
}
__device__ __forceinline__ float bf2f(u16 h){
  return __builtin_bit_cast(float, (u32)h << 16);
}
__device__ __forceinline__ void gl16(const void* g, void* l){
  __builtin_amdgcn_global_load_lds((const __attribute__((address_space(1))) void*)g,
                                   (__attribute__((address_space(3))) void*)l, 16, 0, 0);
}
#define MFMA(a,b,c) __builtin_amdgcn_mfma_f32_16x16x32_bf16((a),(b),(c),0,0,0)

// ---------------- merged weight prep: casts (Wk,Wv,Wo) + Wq'=gamma*Wq (+cq,dq) ----------------
__global__ __launch_bounds__(256) void k_prep(const float* __restrict__ wk,
    const float* __restrict__ wv, const float* __restrict__ wo,
    const float* __restrict__ Wq, const float* __restrict__ gam,
    const float* __restrict__ bet, const float* __restrict__ bq,
    u16* __restrict__ okv, u16* __restrict__ oo,
    u16* __restrict__ wqb, float* __restrict__ cq, float* __restrict__ dq){
  const int t = threadIdx.x;
  if (blockIdx.x < 3072){
    const int sel = blockIdx.x >> 10;
    const int i = ((blockIdx.x & 1023) << 8) + t;
    const float* in = (sel == 0) ? wk : (sel == 1) ? wv : wo;
    u16* o = (sel == 0) ? okv : (sel == 1) ? (okv + 1024 * 1024) : oo;
    float4 v = ((const float4*)in)[i];
    ushort4 r;
    r.x = f2bf(v.x); r.y = f2bf(v.y); r.z = f2bf(v.z); r.w = f2bf(v.w);
    ((ushort4*)o)[i] = r;
  } else {
    const int j = blockIdx.x - 3072;
    const float4 wvq = ((const float4*)(Wq + (size_t)j * 1024))[t];
    const float4 gv = ((const float4*)gam)[t];
    const float4 bv = ((const float4*)bet)[t];
    ushort4 r;
    r.x = f2bf(wvq.x * gv.x); r.y = f2bf(wvq.y * gv.y);
    r.z = f2bf(wvq.z * gv.z); r.w = f2bf(wvq.w * gv.w);
    ((ushort4*)(wqb + (size_t)j * 1024))[t] = r;
    float sc = bf2f(r.x) + bf2f(r.y) + bf2f(r.z) + bf2f(r.w);   // rounded, matches GEMM
    float sd = wvq.x * bv.x + wvq.y * bv.y + wvq.z * bv.z + wvq.w * bv.w;
    #pragma unroll
    for (int o = 1; o < 64; o <<= 1){ sc += __shfl_xor(sc, o); sd += __shfl_xor(sd, o); }
    __shared__ float sm[8];
    const int lane = t & 63, wid = t >> 6;
    if (lane == 0){ sm[wid] = sc; sm[wid + 4] = sd; }
    __syncthreads();
    if (t == 0){
      cq[j] = sm[0] + sm[1] + sm[2] + sm[3];
      dq[j] = sm[4] + sm[5] + sm[6] + sm[7] + bq[j];
    }
  }
}

// ---------------- LayerNorm stats + cast x ----------------
__global__ __launch_bounds__(256) void k_ln(const float* __restrict__ x,
    u16* __restrict__ xbf, float* __restrict__ mur, float* __restrict__ rsd){
  const int row = blockIdx.x, t = threadIdx.x;
  const float4 v = ((const float4*)(x + (size_t)row * HIDD))[t];
  float s  = v.x + v.y + v.z + v.w;
  float ss = v.x*v.x + v.y*v.y + v.z*v.z + v.w*v.w;
  #pragma unroll
  for (int o = 1; o < 64; o <<= 1){ s += __shfl_xor(s, o); ss += __shfl_xor(ss, o); }
  __shared__ float sm[8];
  const int lane = t & 63, wid = t >> 6;
  if (lane == 0){ sm[wid] = s; sm[wid + 4] = ss; }
  __syncthreads();
  s  = sm[0] + sm[1] + sm[2] + sm[3];
  ss = sm[4] + sm[5] + sm[6] + sm[7];
  const float mu   = s * (1.f / 1024.f);
  const float var  = ss * (1.f / 1024.f) - mu * mu;
  const float rstd = rsqrtf(var + 1e-12f);
  if (t == 0){ mur[row] = mu * rstd; rsd[row] = rstd; }
  ushort4 xo;
  xo.x = f2bf(v.x); xo.y = f2bf(v.y); xo.z = f2bf(v.z); xo.w = f2bf(v.w);
  ((ushort4*)(xbf + (size_t)row * HIDD))[t] = xo;
}

// ---------------- 256x256 NT GEMM (r9/r12/r15 structure; SPLIT=1 = 4-phase variant) ----------------
// C[M,N] = A[M,1024]*W[N,1024]^T + bias (+resid bf16). 8 waves (2Mx4N), BK=64, counted
// vmcnt(4), gl_lds staging w/ source swizzle g=(lane&7)^(lane>>3), read granule ^ (lane&7).
// V-half (voutT && n0>=nsplit) stores transposed to vT via [32][66] cep (64B burst/lane).
// Q path (cq set): LN-linearized epilogue v = rstd[row]*acc - murstd[row]*cq[col] + dq[col].
// RES epilogue: fp32 out = acc + bias + bf16-residual (uint4 reads).
struct GP {
  const u16* A; const u16* W; const float* b1; const float* b2;
  int nsplit, lgNB, LDC, nblk; u16* outb; u16* voutT;
  const float* cq; const float* dq; const float* mur; const float* rsd;
};

template<int RES, int SPLIT>
__global__ __launch_bounds__(512, 2) void k_gemm256(GP p0, GP p1, int seg0,
    const u16* __restrict__ residb, float* __restrict__ outf){
  __shared__ union {
    u16 st[2][2][16384];     // [buf][A/B][row*64 + gp*8], 256x64 bf16 each = 128 KiB
    float cep[8][1056];      // per-wave [16][66] f32
    float cep2[8][2112];     // per-wave [32][66] f32 (V transposed path)
  } sm;

  const GP& p = (blockIdx.x < seg0) ? p0 : p1;
  const int bseg = (blockIdx.x < seg0) ? blockIdx.x : blockIdx.x - seg0;
  const u16* __restrict__ A = p.A;
  const u16* __restrict__ W = p.W;
  const int lgNB = p.lgNB, LDC = p.LDC;

  const int wg = ((bseg & 7) * (p.nblk >> 3)) + (bseg >> 3);   // XCD-chunked (nblk % 8 == 0)
  const int m0 = (wg >> lgNB) << 8;
  const int n0 = (wg & ((1 << lgNB) - 1)) << 8;

  const int t = threadIdx.x, lane = t & 63, wid = t >> 6;
  const int ln15 = lane & 15, hi = lane >> 4;
  const int wr = wid >> 2, wc = wid & 3;
  const int lg = lane & 7, lr = lane >> 3;

  auto stage = [&](int buf, int op, const u16* __restrict__ src, int rowoff, int kt){
    #pragma unroll
    for (int i = 0; i < 4; i++){
      const int cb  = ((i << 3) + wid) << 6;
      const int row = (cb >> 3) + lr;
      const int g   = lg ^ lr;
      gl16(src + (size_t)(rowoff + row) * HIDD + (kt << 6) + (g << 3),
           &sm.st[buf][op][cb << 3]);
    }
  };
  auto stageH = [&](int buf, int op, const u16* __restrict__ src, int rowoff, int kt, int half){
    #pragma unroll
    for (int i2 = 0; i2 < 2; i2++){
      const int i = (half << 1) + i2;
      const int cb  = ((i << 3) + wid) << 6;
      const int row = (cb >> 3) + lr;
      const int g   = lg ^ lr;
      gl16(src + (size_t)(rowoff + row) * HIDD + (kt << 6) + (g << 3),
           &sm.st[buf][op][cb << 3]);
    }
  };
  #define RD_A(c,m,ks) (*(const bf16x8*)&sm.st[c][0][(((wr << 7) + ((m) << 4) + ln15) << 6) + \
      (((((ks) << 2) + hi) ^ (lane & 7)) << 3)])
  #define RD_B(c,n,ks) (*(const bf16x8*)&sm.st[c][1][(((wc << 6) + ((n) << 4) + ln15) << 6) + \
      (((((ks) << 2) + hi) ^ (lane & 7)) << 3)])
  #define BARF do { asm volatile("" ::: "memory"); __builtin_amdgcn_s_barrier(); asm volatile("" ::: "memory"); } while(0)

  f32x4 acc[8][4] = {};

  stage(0, 0, A, m0, 0);
  stage(0, 1, W, n0, 0);
  stage(1, 1, W, n0, 1);
  asm volatile("s_waitcnt vmcnt(4)" ::: "memory");
  BARF;

  const int NT = HIDD / 64;
  if constexpr (SPLIT == 0){
    for (int kt = 0; kt < NT; ++kt){
      const int c = kt & 1;
      bf16x8 af[4][2], bq[4][2];
      #pragma unroll
      for (int m = 0; m < 4; m++){ af[m][0] = RD_A(c, m, 0); af[m][1] = RD_A(c, m, 1); }
      #pragma unroll
      for (int n = 0; n < 4; n++){ bq[n][0] = RD_B(c, n, 0); bq[n][1] = RD_B(c, n, 1); }
      const int ka = kt + 1 < NT ? kt + 1 : NT - 1;
      stage(c ^ 1, 0, A, m0, ka);
      __builtin_amdgcn_s_setprio(1);
      #pragma unroll
      for (int m = 0; m < 4; m++)
        #pragma unroll
        for (int n = 0; n < 4; n++){
          acc[m][n] = MFMA(af[m][0], bq[n][0], acc[m][n]);
          acc[m][n] = MFMA(af[m][1], bq[n][1], acc[m][n]);
        }
      __builtin_amdgcn_s_setprio(0);
      BARF;
      #pragma unroll
      for (int m = 0; m < 4; m++){ af[m][0] = RD_A(c, m + 4, 0); af[m][1] = RD_A(c, m + 4, 1); }
      const int kb = kt + 2 < NT ? kt + 2 : NT - 1;
      stage(c, 1, W, n0, kb);
      __builtin_amdgcn_s_setprio(1);
      #pragma unroll
      for (int m = 0; m < 4; m++)
        #pragma unroll
        for (int n = 0; n < 4; n++){
          acc[m + 4][n] = MFMA(af[m][0], bq[n][0], acc[m + 4][n]);
          acc[m + 4][n] = MFMA(af[m][1], bq[n][1], acc[m + 4][n]);
        }
      __builtin_amdgcn_s_setprio(0);
      asm volatile("s_waitcnt vmcnt(4)" ::: "memory");
      BARF;
    }
  } else {
    for (int kt = 0; kt < NT; ++kt){
      const int c = kt & 1;
      const int ka  = kt + 1 < NT ? kt + 1 : NT - 1;
      const int kb2 = kt + 2 < NT ? kt + 2 : NT - 1;
      bf16x8 af[2][2], bq[4][2];
      af[0][0] = RD_A(c, 0, 0); af[0][1] = RD_A(c, 0, 1);
      af[1][0] = RD_A(c, 1, 0); af[1][1] = RD_A(c, 1, 1);
      #pragma unroll
      for (int n = 0; n < 4; n++){ bq[n][0] = RD_B(c, n, 0); bq[n][1] = RD_B(c, n, 1); }
      stageH(c ^ 1, 0, A, m0, ka, 0);
      __builtin_amdgcn_s_setprio(1);
      #pragma unroll
      for (int m = 0; m < 2; m++)
        #pragma unroll
        for (int n = 0; n < 4; n++){
          acc[m][n] = MFMA(af[m][0], bq[n][0], acc[m][n]);
          acc[m][n] = MFMA(af[m][1], bq[n][1], acc[m][n]);
        }
      __builtin_amdgcn_s_setprio(0);
      BARF;
      af[0][0] = RD_A(c, 2, 0); af[0][1] = RD_A(c, 2, 1);
      af[1][0] = RD_A(c, 3, 0); af[1][1] = RD_A(c, 3, 1);
      stageH(c ^ 1, 0, A, m0, ka, 1);
      __builtin_amdgcn_s_setprio(1);
      #pragma unroll
      for (int m = 0; m < 2; m++)
        #pragma unroll
        for (int n = 0; n < 4; n++){
          acc[m + 2][n] = MFMA(af[m][0], bq[n][0], acc[m + 2][n]);
          acc[m + 2][n] = MFMA(af[m][1], bq[n][1], acc[m + 2][n]);
        }
      __builtin_amdgcn_s_setprio(0);
      BARF;
      af[0][0] = RD_A(c, 4, 0); af[0][1] = RD_A(c, 4, 1);
      af[1][0] = RD_A(c, 5, 0); af[1][1] = RD_A(c, 5, 1);
      stageH(c, 1, W, n0, kb2, 0);
      __builtin_amdgcn_s_setprio(1);
      #pragma unroll
      for (int m = 0; m < 2; m++)
        #pragma unroll
        for (int n = 0; n < 4; n++){
          acc[m + 4][n] = MFMA(af[m][0], bq[n][0], acc[m + 4][n]);
          acc[m + 4][n] = MFMA(af[m][1], bq[n][1], acc[m + 4][n]);
        }
      __builtin_amdgcn_s_setprio(0);
      BARF;
      af[0][0] = RD_A(c, 6, 0); af[0][1] = RD_A(c, 6, 1);
      af[1][0] = RD_A(c, 7, 0); af[1][1] = RD_A(c, 7, 1);
      stageH(c, 1, W, n0, kb2, 1);
      __builtin_amdgcn_s_setprio(1);
      #pragma unroll
      for (int m = 0; m < 2; m++)
        #pragma unroll
        for (int n = 0; n < 4; n++){
          acc[m + 6][n] = MFMA(af[m][0], bq[n][0], acc[m + 6][n]);
          acc[m + 6][n] = MFMA(af[m][1], bq[n][1], acc[m + 6][n]);
        }
      __builtin_amdgcn_s_setprio(0);
      asm volatile("s_waitcnt vmcnt(4)" ::: "memory");
      BARF;
    }
  }
  #undef RD_A
  #undef RD_B

  asm volatile("s_waitcnt vmcnt(0)" ::: "memory");
  BARF;

  const float* bp = (n0 < p.nsplit) ? p.b1 : (p.b2 - p.nsplit);
  float bn[4];
  #pragma unroll
  for (int n = 0; n < 4; n++) bn[n] = bp[n0 + (wc << 6) + (n << 4) + ln15];

  if constexpr (RES){
    float* cw = &sm.cep[wid][0];
    const int rr = lane >> 3, cb8 = (lane & 7) << 3;
    #pragma unroll
    for (int m = 0; m < 8; m++){
      #pragma unroll
      for (int n = 0; n < 4; n++)
        #pragma unroll
        for (int r = 0; r < 4; r++)
          cw[((hi << 2) + r) * 66 + (n << 4) + ln15] = acc[m][n][r] + bn[n];
      #pragma unroll
      for (int j = 0; j < 2; j++){
        const int row = (j << 3) + rr;
        const size_t gr = (size_t)(m0 + (wr << 7) + (m << 4) + row);
        const size_t gidx = gr * LDC + n0 + (wc << 6) + cb8;
        const size_t ridx = gr * HIDD + n0 + (wc << 6) + cb8;
        const uint4 rv = *(const uint4*)&residb[ridx];
        const u32 rr4[4] = {rv.x, rv.y, rv.z, rv.w};
        float4 o0, o1;
        o0.x = cw[row * 66 + cb8 + 0] + bf2f((u16)(rr4[0] & 0xffff));
        o0.y = cw[row * 66 + cb8 + 1] + bf2f((u16)(rr4[0] >> 16));
        o0.z = cw[row * 66 + cb8 + 2] + bf2f((u16)(rr4[1] & 0xffff));
        o0.w = cw[row * 66 + cb8 + 3] + bf2f((u16)(rr4[1] >> 16));
        o1.x = cw[row * 66 + cb8 + 4] + bf2f((u16)(rr4[2] & 0xffff));
        o1.y = cw[row * 66 + cb8 + 5] + bf2f((u16)(rr4[2] >> 16));
        o1.z = cw[row * 66 + cb8 + 6] + bf2f((u16)(rr4[3] & 0xffff));
        o1.w = cw[row * 66 + cb8 + 7] + bf2f((u16)(rr4[3] >> 16));
        *(float4*)&outf[gidx]     = o0;
        *(float4*)&outf[gidx + 4] = o1;
      }
    }
  } else if (p.voutT != nullptr && n0 >= p.nsplit){
    // V half: store transposed to vT[((b*16+h)*64 + d)*SQ + s], 64B burst per lane
    float* cw = &sm.cep2[wid][0];                 // [32][66]
    const int e0 = n0 - p.nsplit + (wc << 6);
    const int hh = e0 >> 6;
    u16* vt = p.voutT;
    #pragma unroll
    for (int mp = 0; mp < 4; mp++){
      #pragma unroll
      for (int mh = 0; mh < 2; mh++){
        const int m = (mp << 1) + mh;
        #pragma unroll
        for (int n = 0; n < 4; n++)
          #pragma unroll
          for (int r = 0; r < 4; r++)
            cw[((mh << 4) + (hi << 2) + r) * 66 + (n << 4) + ln15] = acc[m][n][r] + bn[n];
      }
      const int rg0 = m0 + (wr << 7) + (mp << 5);
      const int bb = rg0 >> 12, s0 = rg0 & 4095;
      u16* dst = vt + (((size_t)(bb << 4) + hh) * 64 + lane) * SQ + s0;
      #pragma unroll
      for (int j = 0; j < 4; j++){
        u32 ro[4];
        #pragma unroll
        for (int q = 0; q < 4; q++){
          float v0 = cw[((j << 3) + 2 * q    ) * 66 + lane];
          float v1 = cw[((j << 3) + 2 * q + 1) * 66 + lane];
          ro[q] = (u32)f2bf(v0) | ((u32)f2bf(v1) << 16);
        }
        uint4 o; o.x = ro[0]; o.y = ro[1]; o.z = ro[2]; o.w = ro[3];
        *(uint4*)&dst[j << 3] = o;
      }
    }
  } else {
    float* cw = &sm.cep[wid][0];
    const int rr = lane >> 3, cb8 = (lane & 7) << 3;
    u16* outb = p.outb;
    if (p.cq != nullptr){
      // Q path: LN-linearized correction, then bf16 row-major store
      float cqn[4], dqn[4];
      #pragma unroll
      for (int n = 0; n < 4; n++){
        const int col = n0 + (wc << 6) + (n << 4) + ln15;
        cqn[n] = p.cq[col]; dqn[n] = p.dq[col];
      }
      #pragma unroll
      for (int m = 0; m < 8; m++){
        #pragma unroll
        for (int r = 0; r < 4; r++){
          const int grow = m0 + (wr << 7) + (m << 4) + (hi << 2) + r;
          const float mu = p.mur[grow], rs = p.rsd[grow];
          #pragma unroll
          for (int n = 0; n < 4; n++)
            cw[((hi << 2) + r) * 66 + (n << 4) + ln15] = rs * acc[m][n][r] - mu * cqn[n] + dqn[n];
        }
        #pragma unroll
        for (int j = 0; j < 2; j++){
          const int row = (j << 3) + rr;
          u32 ro[4];
          #pragma unroll
          for (int pq = 0; pq < 4; pq++){
            float v0 = cw[row * 66 + cb8 + 2 * pq];
            float v1 = cw[row * 66 + cb8 + 2 * pq + 1];
            ro[pq] = (u32)f2bf(v0) | ((u32)f2bf(v1) << 16);
          }
          uint4 o; o.x = ro[0]; o.y = ro[1]; o.z = ro[2]; o.w = ro[3];
          *(uint4*)&outb[(size_t)(m0 + (wr << 7) + (m << 4) + row) * LDC
                         + n0 + (wc << 6) + cb8] = o;
        }
      }
    } else {
      #pragma unroll
      for (int m = 0; m < 8; m++){
        #pragma unroll
        for (int n = 0; n < 4; n++)
          #pragma unroll
          for (int r = 0; r < 4; r++)
            cw[((hi << 2) + r) * 66 + (n << 4) + ln15] = acc[m][n][r] + bn[n];
        #pragma unroll
        for (int j = 0; j < 2; j++){
          const int row = (j << 3) + rr;
          u32 ro[4];
          #pragma unroll
          for (int pq = 0; pq < 4; pq++){
            float v0 = cw[row * 66 + cb8 + 2 * pq];
            float v1 = cw[row * 66 + cb8 + 2 * pq + 1];
            ro[pq] = (u32)f2bf(v0) | ((u32)f2bf(v1) << 16);
          }
          uint4 o; o.x = ro[0]; o.y = ro[1]; o.z = ro[2]; o.w = ro[3];
          *(uint4*)&outb[(size_t)(m0 + (wr << 7) + (m << 4) + row) * LDC
                         + n0 + (wc << 6) + cb8] = o;
        }
      }
    }
  }
  #undef BARF
}

// ---------------- transpose K: kb [B,S,1024] -> ekT [B,H,64,S] with elu+L2norm ----------------
__global__ __launch_bounds__(256) void k_transposeK(const u16* __restrict__ kb,
                                                    u16* __restrict__ ekT){
  __shared__ float tile[64][65];
  __shared__ float pr[64][4];
  __shared__ float rn[64];
  const int sb = blockIdx.x << 6, h = blockIdx.y, b = blockIdx.z;
  const int t = threadIdx.x;
  {
    const int tok = t >> 2, q = t & 3;
    const u16* src = kb + (size_t)(b * SQ + sb + tok) * 1024 + (h << 6) + (q << 4);
    uint4 u0 = *(const uint4*)src;
    uint4 u1 = *(const uint4*)(src + 8);
    u32 uu[8] = {u0.x, u0.y, u0.z, u0.w, u1.x, u1.y, u1.z, u1.w};
    float ss = 0.f;
    #pragma unroll
    for (int i = 0; i < 8; i++){
      float f0 = bf2f((u16)(uu[i] & 0xffff));
      float f1 = bf2f((u16)(uu[i] >> 16));
      f0 = f0 > 0.f ? f0 : expm1f(f0);
      f1 = f1 > 0.f ? f1 : expm1f(f1);
      ss += f0 * f0 + f1 * f1;
      tile[tok][(q << 4) + 2*i]     = f0;
      tile[tok][(q << 4) + 2*i + 1] = f1;
    }
    pr[tok][q] = ss;
  }
  __syncthreads();
  if (t < 64) rn[t] = rsqrtf(pr[t][0] + pr[t][1] + pr[t][2] + pr[t][3]);
  __syncthreads();
  const int d = t >> 2, sq2 = (t & 3) << 4;
  u16* dst = ekT + ((size_t)(b * NHQ + h) * 64 + d) * SQ + sb + sq2;
  u32 ro[8];
  #pragma unroll
  for (int i = 0; i < 8; i++){
    float v0 = tile[sq2 + 2*i][d]     * rn[sq2 + 2*i];
    float v1 = tile[sq2 + 2*i + 1][d] * rn[sq2 + 2*i + 1];
    ro[i] = (u32)f2bf(v0) | ((u32)f2bf(v1) << 16);
  }
  uint4 o0; o0.x = ro[0]; o0.y = ro[1]; o0.z = ro[2]; o0.w = ro[3];
  uint4 o1; o1.x = ro[4]; o1.y = ro[5]; o1.z = ro[6]; o1.w = ro[7];
  *(uint4*)dst = o0;
  *(uint4*)(dst + 8) = o1;
}

// ---------------- kv split-K: per (b,h,half) partial[e][d] = sum_{s in half} v[s][e] ek[s][d] ----------------
// 256 blocks (2 per bh) -> full-GPU occupancy. f32 partials; k_kvr reduces.
__global__ __launch_bounds__(256) void k_kv(const u16* __restrict__ vT, const u16* __restrict__ ekT,
                                            float* __restrict__ kvP){
  const int half = blockIdx.x & 1, bh = blockIdx.x >> 1;
  const u16* Av = vT  + (size_t)bh * 64 * SQ;
  const u16* Bk = ekT + (size_t)bh * 64 * SQ;
  const int lane = threadIdx.x & 63, wid = threadIdx.x >> 6;
  const int ln15 = lane & 15, hi = lane >> 4;
  f32x4 acc[4][4] = {};
  const int kb = (half << 11) + (wid << 9);
  for (int ks = 0; ks < 16; ++ks){
    const int k0 = kb + (ks << 5) + (hi << 3);
    bf16x8 af[4], bfr[4];
    #pragma unroll
    for (int m = 0; m < 4; m++) af[m]  = *(const bf16x8*)(Av + (size_t)((m << 4) + ln15) * SQ + k0);
    #pragma unroll
    for (int n = 0; n < 4; n++) bfr[n] = *(const bf16x8*)(Bk + (size_t)((n << 4) + ln15) * SQ + k0);
    #pragma unroll
    for (int m = 0; m < 4; m++)
      #pragma unroll
      for (int n = 0; n < 4; n++)
        acc[m][n] = MFMA(af[m], bfr[n], acc[m][n]);
  }
  __shared__ float red[64][64];
  for (int w = 0; w < 4; ++w){
    if (wid == w){
      #pragma unroll
      for (int m = 0; m < 4; m++)
        #pragma unroll
        for (int n = 0; n < 4; n++)
          #pragma unroll
          for (int r = 0; r < 4; r++){
            int row = (m << 4) + (hi << 2) + r;
            int col = (n << 4) + ln15;
            if (w == 0) red[row][col] = acc[m][n][r];
            else        red[row][col] += acc[m][n][r];
          }
    }
    __syncthreads();
  }
  float* dst = kvP + (size_t)blockIdx.x * 4096;
  const int tt = threadIdx.x;
  #pragma unroll
  for (int i = 0; i < 16; i++){
    int idx = tt * 16 + i;
    dst[idx] = red[idx >> 6][idx & 63];
  }
}

// ---------------- kvr: kvT = bf16((p0 + p1) * 0.125) ----------------
__global__ __launch_bounds__(256) void k_kvr(const float* __restrict__ kvP,
                                             u16* __restrict__ kvT){
  const int bh = blockIdx.x, t = threadIdx.x;
  const float* p0 = kvP + (size_t)(bh << 1) * 4096;
  const float* p1 = p0 + 4096;
  u16* dst = kvT + (size_t)bh * 4096;
  #pragma unroll
  for (int i = 0; i < 2; i++){
    const int idx = (i << 11) + (t << 3);
    const float4 a0 = *(const float4*)&p0[idx];
    const float4 a1 = *(const float4*)&p0[idx + 4];
    const float4 b0 = *(const float4*)&p1[idx];
    const float4 b1 = *(const float4*)&p1[idx + 4];
    u32 ro[4];
    ro[0] = (u32)f2bf((a0.x + b0.x) * 0.125f) | ((u32)f2bf((a0.y + b0.y) * 0.125f) << 16);
    ro[1] = (u32)f2bf((a0.z + b0.z) * 0.125f) | ((u32)f2bf((a0.w + b0.w) * 0.125f) << 16);
    ro[2] = (u32)f2bf((a1.x + b1.x) * 0.125f) | ((u32)f2bf((a1.y + b1.y) * 0.125f) << 16);
    ro[3] = (u32)f2bf((a1.z + b1.z) * 0.125f) | ((u32)f2bf((a1.w + b1.w) * 0.125f) << 16);
    uint4 o; o.x = ro[0]; o.y = ro[1]; o.z = ro[2]; o.w = ro[3];
    *(uint4*)&dst[idx] = o;
  }
}

// ---------------- ctx (+ fused elu/L2norm on q): ctx[s][e] = sum_d eq[s][d] * kv[d][e] ----------------
__global__ __launch_bounds__(256) void k_ctx(const u16* __restrict__ q, const u16* __restrict__ kvT,
                                             u16* __restrict__ ctx){
  __shared__ u16 Alds[1024 * 8];
  __shared__ u16 Blds[512 * 8];
  __shared__ float prn[128][2];
  const int sb = blockIdx.x << 7;
  const int h = blockIdx.y, b = blockIdx.z;
  const int bh = (b << 4) + h;
  const int t = threadIdx.x, lane = t & 63, wid = t >> 6;
  const int ln15 = lane & 15, hi = lane >> 4;
  {
    uint4 va[4]; uint4 vb[2];
    #pragma unroll
    for (int i = 0; i < 4; i++){
      int c = (wid << 6) + (i << 8) + lane;
      int g = c >> 7, row = c & 127;
      va[i] = *(const uint4*)(q + (size_t)(b * SQ + sb + row) * HIDD + (h << 6) + g * 8);
    }
    #pragma unroll
    for (int i = 0; i < 2; i++){
      int c = (wid << 6) + (i << 8) + lane;
      int g = c >> 6, row = c & 63;
      vb[i] = *(const uint4*)(kvT + (size_t)bh * 4096 + (row << 6) + g * 8);
    }
    #pragma unroll
    for (int i = 0; i < 4; i++)
      *(uint4*)&Alds[((wid << 6) + (i << 8) + lane) * 8] = va[i];
    #pragma unroll
    for (int i = 0; i < 2; i++)
      *(uint4*)&Blds[((wid << 6) + (i << 8) + lane) * 8] = vb[i];
  }
  __syncthreads();
  {
    const int row = t & 127, half = t >> 7;
    float vals[4][8]; float ss = 0.f;
    #pragma unroll
    for (int g4 = 0; g4 < 4; g4++){
      const int g = (half << 2) + g4;
      uint4 u = *(const uint4*)&Alds[((g << 7) + row) * 8];
      u32 uu[4] = {u.x, u.y, u.z, u.w};
      #pragma unroll
      for (int i = 0; i < 4; i++){
        float f0 = bf2f((u16)(uu[i] & 0xffff));
        float f1 = bf2f((u16)(uu[i] >> 16));
        f0 = f0 > 0.f ? f0 : expm1f(f0);
        f1 = f1 > 0.f ? f1 : expm1f(f1);
        vals[g4][2*i] = f0; vals[g4][2*i+1] = f1;
        ss += f0 * f0 + f1 * f1;
      }
    }
    prn[row][half] = ss;
    __syncthreads();
    const float rn = rsqrtf(prn[row][0] + prn[row][1]);
    #pragma unroll
    for (int g4 = 0; g4 < 4; g4++){
      const int g = (half << 2) + g4;
      u32 ro[4];
      #pragma unroll
      for (int i = 0; i < 4; i++)
        ro[i] = (u32)f2bf(vals[g4][2*i] * rn) | ((u32)f2bf(vals[g4][2*i+1] * rn) << 16);
      uint4 o; o.x = ro[0]; o.y = ro[1]; o.z = ro[2]; o.w = ro[3];
      *(uint4*)&Alds[((g << 7) + row) * 8] = o;
    }
  }
  __syncthreads();
  f32x4 acc[2][4] = {};
  #pragma unroll
  for (int k2 = 0; k2 < 2; k2++){
    const int g = (k2 << 2) + hi;
    bf16x8 af[2], bfr[4];
    #pragma unroll
    for (int m = 0; m < 2; m++) af[m]  = *(const bf16x8*)&Alds[((g << 7) + (wid << 5) + (m << 4) + ln15) * 8];
    #pragma unroll
    for (int n = 0; n < 4; n++) bfr[n] = *(const bf16x8*)&Blds[((g << 6) + (n << 4) + ln15) * 8];
    #pragma unroll
    for (int m = 0; m < 2; m++)
      #pragma unroll
      for (int n = 0; n < 4; n++)
        acc[m][n] = MFMA(af[m], bfr[n], acc[m][n]);
  }
  #pragma unroll
  for (int m = 0; m < 2; m++)
    #pragma unroll
    for (int n = 0; n < 4; n++)
      #pragma unroll
      for (int r = 0; r < 4; r++){
        int srow = sb + (wid << 5) + (m << 4) + (hi << 2) + r;
        int col  = (n << 4) + ln15;
        ctx[(size_t)(b * SQ + srow) * HIDD + (h << 6) + col] = f2bf(acc[m][n][r]);
      }
}

extern "C" void kernel_launch(void* const* d_in, const int* in_sizes, int n_in,
                              void* d_out, int out_size, void* d_ws, size_t ws_size,
                              hipStream_t stream){
  const float* x   = (const float*)d_in[0];
  const float* lng = (const float*)d_in[2];
  const float* lnb = (const float*)d_in[3];
  const float* Wq  = (const float*)d_in[4];
  const float* bq  = (const float*)d_in[5];
  const float* Wk  = (const float*)d_in[6];
  const float* bk  = (const float*)d_in[7];
  const float* Wv  = (const float*)d_in[8];
  const float* bv  = (const float*)d_in[9];
  const float* Wo  = (const float*)d_in[10];
  const float* bo  = (const float*)d_in[11];
  float* out = (float*)d_out;

  char* w = (char*)d_ws;
  const size_t MB = 1ull << 20;
  u16* wqb  = (u16*)(w + 0   * MB);   // 2 MiB: Wq' = gamma*Wq (bf16)
  u16* wkvb = (u16*)(w + 2   * MB);   // 4 MiB: [Wk; Wv] stacked [2048][1024]
  u16* wob  = (u16*)(w + 6   * MB);   // 2 MiB
  u16* xbf  = (u16*)(w + 8   * MB);   // 64 MiB (live through out-GEMM: bf16 residual)
  u16* xnbf = (u16*)(w + 72  * MB);   // 64 MiB (ekT scratch)
  u16* qb   = (u16*)(w + 136 * MB);   // 64 MiB (raw q; elu+norm fused into k_ctx)
  u16* kb   = (u16*)(w + 200 * MB);   // 64 MiB (raw k, row-major)
  u16* vT   = (u16*)(w + 264 * MB);   // 64 MiB (v transposed [B,H,64,S], direct from GEMM)
  u16* kvT  = (u16*)(w + 328 * MB);   // 1 MiB
  float* murstd = (float*)(w + 330 * MB);  // 128 KiB
  float* rstdv  = (float*)(w + 331 * MB);  // 128 KiB
  float* cqv    = (float*)(w + 332 * MB);  // 4 KiB
  float* dqv    = (float*)(w + 333 * MB);  // 4 KiB
  float* kvP    = (float*)(w + 336 * MB);  // 4 MiB f32 split-K partials
  // aliases (stream-ordered lifetimes)
  u16* ekT = xnbf;
  u16* ctx = kb;    // kb dead after k_transposeK

  k_prep<<<4096, 256, 0, stream>>>(Wk, Wv, Wo, Wq, lng, lnb, bq, wkvb, wob, wqb, cqv, dqv);
  k_ln<<<TOKN, 256, 0, stream>>>(x, xbf, murstd, rstdv);

  // merged Q + KV GEMM (2-phase): Q blocks [0,512) with A=xbf + LN-linearized epilogue;
  // KV blocks [512,1536): K half -> kb row-major; V half -> vT transposed
  GP pq  = { xbf, wqb,  bq, bq, 1 << 30, 2, 1024, 512,  qb, nullptr, cqv, dqv, murstd, rstdv };
  GP pkv = { xbf, wkvb, bk, bv, 1024,    3, 1024, 1024, kb, vT,      nullptr, nullptr, nullptr, nullptr };
  k_gemm256<0, 0><<<1536, 512, 0, stream>>>(pq, pkv, 512, nullptr, nullptr);

  k_transposeK<<<dim3(64, 16, 8), 256, 0, stream>>>(kb, ekT);
  k_kv<<<256, 256, 0, stream>>>(vT, ekT, kvP);
  k_kvr<<<128, 256, 0, stream>>>(kvP, kvT);
  k_ctx<<<dim3(32, 16, 8), 256, 0, stream>>>(qb, kvT, ctx);

  // out GEMM (4-phase): bf16 residual from xbf + fp32 out
  GP po = { ctx, wob, bo, bo, 1 << 30, 2, 1024, 512, nullptr, nullptr,
            nullptr, nullptr, nullptr, nullptr };
  k_gemm256<1, 1><<<512, 512, 0, stream>>>(po, po, 512, xbf, out);

  (void)in_sizes; (void)n_in; (void)out_size; (void)ws_size;
}

// Round 22
// 653.295 us; speedup vs baseline: 1.0458x; 1.0075x over previous
//
#include <hip/hip_runtime.h>

typedef unsigned short u16;
typedef unsigned int   u32;
typedef __attribute__((ext_vector_type(8))) __bf16 bf16x8;
typedef __attribute__((ext_vector_type(4))) float  f32x4;

#define BQ   8
#define SQ   4096
#define NHQ  16
#define HIDD 1024
#define TOKN 32768

__device__ __forceinline__ u16 f2bf(float f){
  u32 u = __builtin_bit_cast(u32, f);
  u += 0x7fffu + ((u >> 16) & 1u);
  return (u16)(u >> 16);
}
__device__ __forceinline__ float bf2f(u16 h){
  return __builtin_bit_cast(float, (u32)h << 16);
}
__device__ __forceinline__ void gl16(const void* g, void* l){
  __builtin_amdgcn_global_load_lds((const __attribute__((address_space(1))) void*)g,
                                   (__attribute__((address_space(3))) void*)l, 16, 0, 0);
}
#define MFMA(a,b,c) __builtin_amdgcn_mfma_f32_16x16x32_bf16((a),(b),(c),0,0,0)

// ---------------- merged head: LN stats + cast x  ||  weight casts + Wq' prep ----------------
// blocks [0, 32768): LayerNorm row blocks; [32768, 35840): Wk/Wv/Wo casts; [35840, 36864): Wq'.
__global__ __launch_bounds__(256) void k_head(const float* __restrict__ x,
    u16* __restrict__ xbf, float* __restrict__ mur, float* __restrict__ rsd,
    const float* __restrict__ wk, const float* __restrict__ wv, const float* __restrict__ wo,
    const float* __restrict__ Wq, const float* __restrict__ gam,
    const float* __restrict__ bet, const float* __restrict__ bq,
    u16* __restrict__ okv, u16* __restrict__ oo,
    u16* __restrict__ wqb, float* __restrict__ cq, float* __restrict__ dq){
  const int t = threadIdx.x;
  if (blockIdx.x < TOKN){
    const int row = blockIdx.x;
    const float4 v = ((const float4*)(x + (size_t)row * HIDD))[t];
    float s  = v.x + v.y + v.z + v.w;
    float ss = v.x*v.x + v.y*v.y + v.z*v.z + v.w*v.w;
    #pragma unroll
    for (int o = 1; o < 64; o <<= 1){ s += __shfl_xor(s, o); ss += __shfl_xor(ss, o); }
    __shared__ float sm[8];
    const int lane = t & 63, wid = t >> 6;
    if (lane == 0){ sm[wid] = s; sm[wid + 4] = ss; }
    __syncthreads();
    s  = sm[0] + sm[1] + sm[2] + sm[3];
    ss = sm[4] + sm[5] + sm[6] + sm[7];
    const float mu   = s * (1.f / 1024.f);
    const float var  = ss * (1.f / 1024.f) - mu * mu;
    const float rstd = rsqrtf(var + 1e-12f);
    if (t == 0){ mur[row] = mu * rstd; rsd[row] = rstd; }
    ushort4 xo;
    xo.x = f2bf(v.x); xo.y = f2bf(v.y); xo.z = f2bf(v.z); xo.w = f2bf(v.w);
    ((ushort4*)(xbf + (size_t)row * HIDD))[t] = xo;
  } else if (blockIdx.x < TOKN + 3072){
    const int bb = blockIdx.x - TOKN;
    const int sel = bb >> 10;
    const int i = ((bb & 1023) << 8) + t;
    const float* in = (sel == 0) ? wk : (sel == 1) ? wv : wo;
    u16* o = (sel == 0) ? okv : (sel == 1) ? (okv + 1024 * 1024) : oo;
    float4 v = ((const float4*)in)[i];
    ushort4 r;
    r.x = f2bf(v.x); r.y = f2bf(v.y); r.z = f2bf(v.z); r.w = f2bf(v.w);
    ((ushort4*)o)[i] = r;
  } else {
    const int j = blockIdx.x - (TOKN + 3072);
    const float4 wvq = ((const float4*)(Wq + (size_t)j * 1024))[t];
    const float4 gv = ((const float4*)gam)[t];
    const float4 bv = ((const float4*)bet)[t];
    ushort4 r;
    r.x = f2bf(wvq.x * gv.x); r.y = f2bf(wvq.y * gv.y);
    r.z = f2bf(wvq.z * gv.z); r.w = f2bf(wvq.w * gv.w);
    ((ushort4*)(wqb + (size_t)j * 1024))[t] = r;
    float sc = bf2f(r.x) + bf2f(r.y) + bf2f(r.z) + bf2f(r.w);   // rounded, matches GEMM
    float sd = wvq.x * bv.x + wvq.y * bv.y + wvq.z * bv.z + wvq.w * bv.w;
    #pragma unroll
    for (int o = 1; o < 64; o <<= 1){ sc += __shfl_xor(sc, o); sd += __shfl_xor(sd, o); }
    __shared__ float sm2[8];
    const int lane = t & 63, wid = t >> 6;
    if (lane == 0){ sm2[wid] = sc; sm2[wid + 4] = sd; }
    __syncthreads();
    if (t == 0){
      cq[j] = sm2[0] + sm2[1] + sm2[2] + sm2[3];
      dq[j] = sm2[4] + sm2[5] + sm2[6] + sm2[7] + bq[j];
    }
  }
}

// ---------------- 256x256 NT GEMM (r9/r12/r15 structure; SPLIT=1 = 4-phase variant) ----------------
// C[M,N] = A[M,1024]*W[N,1024]^T + bias (+resid bf16). 8 waves (2Mx4N), BK=64, counted
// vmcnt(4), gl_lds staging w/ source swizzle g=(lane&7)^(lane>>3), read granule ^ (lane&7).
// V-half (voutT && n0>=nsplit) stores transposed to vT via [32][66] cep (64B burst/lane).
// Q path (cq set): LN-linearized epilogue v = rstd[row]*acc - murstd[row]*cq[col] + dq[col].
// RES epilogue: fp32 out = acc + bias + bf16-residual (uint4 reads).
struct GP {
  const u16* A; const u16* W; const float* b1; const float* b2;
  int nsplit, lgNB, LDC, nblk; u16* outb; u16* voutT;
  const float* cq; const float* dq; const float* mur; const float* rsd;
};

template<int RES, int SPLIT>
__global__ __launch_bounds__(512, 2) void k_gemm256(GP p0, GP p1, int seg0,
    const u16* __restrict__ residb, float* __restrict__ outf){
  __shared__ union {
    u16 st[2][2][16384];     // [buf][A/B][row*64 + gp*8], 256x64 bf16 each = 128 KiB
    float cep[8][1056];      // per-wave [16][66] f32
    float cep2[8][2112];     // per-wave [32][66] f32 (V transposed path)
  } sm;

  const GP& p = (blockIdx.x < seg0) ? p0 : p1;
  const int bseg = (blockIdx.x < seg0) ? blockIdx.x : blockIdx.x - seg0;
  const u16* __restrict__ A = p.A;
  const u16* __restrict__ W = p.W;
  const int lgNB = p.lgNB, LDC = p.LDC;

  const int wg = ((bseg & 7) * (p.nblk >> 3)) + (bseg >> 3);   // XCD-chunked (nblk % 8 == 0)
  const int m0 = (wg >> lgNB) << 8;
  const int n0 = (wg & ((1 << lgNB) - 1)) << 8;

  const int t = threadIdx.x, lane = t & 63, wid = t >> 6;
  const int ln15 = lane & 15, hi = lane >> 4;
  const int wr = wid >> 2, wc = wid & 3;
  const int lg = lane & 7, lr = lane >> 3;

  auto stage = [&](int buf, int op, const u16* __restrict__ src, int rowoff, int kt){
    #pragma unroll
    for (int i = 0; i < 4; i++){
      const int cb  = ((i << 3) + wid) << 6;
      const int row = (cb >> 3) + lr;
      const int g   = lg ^ lr;
      gl16(src + (size_t)(rowoff + row) * HIDD + (kt << 6) + (g << 3),
           &sm.st[buf][op][cb << 3]);
    }
  };
  auto stageH = [&](int buf, int op, const u16* __restrict__ src, int rowoff, int kt, int half){
    #pragma unroll
    for (int i2 = 0; i2 < 2; i2++){
      const int i = (half << 1) + i2;
      const int cb  = ((i << 3) + wid) << 6;
      const int row = (cb >> 3) + lr;
      const int g   = lg ^ lr;
      gl16(src + (size_t)(rowoff + row) * HIDD + (kt << 6) + (g << 3),
           &sm.st[buf][op][cb << 3]);
    }
  };
  #define RD_A(c,m,ks) (*(const bf16x8*)&sm.st[c][0][(((wr << 7) + ((m) << 4) + ln15) << 6) + \
      (((((ks) << 2) + hi) ^ (lane & 7)) << 3)])
  #define RD_B(c,n,ks) (*(const bf16x8*)&sm.st[c][1][(((wc << 6) + ((n) << 4) + ln15) << 6) + \
      (((((ks) << 2) + hi) ^ (lane & 7)) << 3)])
  #define BARF do { asm volatile("" ::: "memory"); __builtin_amdgcn_s_barrier(); asm volatile("" ::: "memory"); } while(0)

  f32x4 acc[8][4] = {};

  stage(0, 0, A, m0, 0);
  stage(0, 1, W, n0, 0);
  stage(1, 1, W, n0, 1);
  asm volatile("s_waitcnt vmcnt(4)" ::: "memory");
  BARF;

  const int NT = HIDD / 64;
  if constexpr (SPLIT == 0){
    for (int kt = 0; kt < NT; ++kt){
      const int c = kt & 1;
      bf16x8 af[4][2], bq[4][2];
      #pragma unroll
      for (int m = 0; m < 4; m++){ af[m][0] = RD_A(c, m, 0); af[m][1] = RD_A(c, m, 1); }
      #pragma unroll
      for (int n = 0; n < 4; n++){ bq[n][0] = RD_B(c, n, 0); bq[n][1] = RD_B(c, n, 1); }
      const int ka = kt + 1 < NT ? kt + 1 : NT - 1;
      stage(c ^ 1, 0, A, m0, ka);
      __builtin_amdgcn_s_setprio(1);
      #pragma unroll
      for (int m = 0; m < 4; m++)
        #pragma unroll
        for (int n = 0; n < 4; n++){
          acc[m][n] = MFMA(af[m][0], bq[n][0], acc[m][n]);
          acc[m][n] = MFMA(af[m][1], bq[n][1], acc[m][n]);
        }
      __builtin_amdgcn_s_setprio(0);
      BARF;
      #pragma unroll
      for (int m = 0; m < 4; m++){ af[m][0] = RD_A(c, m + 4, 0); af[m][1] = RD_A(c, m + 4, 1); }
      const int kb = kt + 2 < NT ? kt + 2 : NT - 1;
      stage(c, 1, W, n0, kb);
      __builtin_amdgcn_s_setprio(1);
      #pragma unroll
      for (int m = 0; m < 4; m++)
        #pragma unroll
        for (int n = 0; n < 4; n++){
          acc[m + 4][n] = MFMA(af[m][0], bq[n][0], acc[m + 4][n]);
          acc[m + 4][n] = MFMA(af[m][1], bq[n][1], acc[m + 4][n]);
        }
      __builtin_amdgcn_s_setprio(0);
      asm volatile("s_waitcnt vmcnt(4)" ::: "memory");
      BARF;
    }
  } else {
    for (int kt = 0; kt < NT; ++kt){
      const int c = kt & 1;
      const int ka  = kt + 1 < NT ? kt + 1 : NT - 1;
      const int kb2 = kt + 2 < NT ? kt + 2 : NT - 1;
      bf16x8 af[2][2], bq[4][2];
      af[0][0] = RD_A(c, 0, 0); af[0][1] = RD_A(c, 0, 1);
      af[1][0] = RD_A(c, 1, 0); af[1][1] = RD_A(c, 1, 1);
      #pragma unroll
      for (int n = 0; n < 4; n++){ bq[n][0] = RD_B(c, n, 0); bq[n][1] = RD_B(c, n, 1); }
      stageH(c ^ 1, 0, A, m0, ka, 0);
      __builtin_amdgcn_s_setprio(1);
      #pragma unroll
      for (int m = 0; m < 2; m++)
        #pragma unroll
        for (int n = 0; n < 4; n++){
          acc[m][n] = MFMA(af[m][0], bq[n][0], acc[m][n]);
          acc[m][n] = MFMA(af[m][1], bq[n][1], acc[m][n]);
        }
      __builtin_amdgcn_s_setprio(0);
      BARF;
      af[0][0] = RD_A(c, 2, 0); af[0][1] = RD_A(c, 2, 1);
      af[1][0] = RD_A(c, 3, 0); af[1][1] = RD_A(c, 3, 1);
      stageH(c ^ 1, 0, A, m0, ka, 1);
      __builtin_amdgcn_s_setprio(1);
      #pragma unroll
      for (int m = 0; m < 2; m++)
        #pragma unroll
        for (int n = 0; n < 4; n++){
          acc[m + 2][n] = MFMA(af[m][0], bq[n][0], acc[m + 2][n]);
          acc[m + 2][n] = MFMA(af[m][1], bq[n][1], acc[m + 2][n]);
        }
      __builtin_amdgcn_s_setprio(0);
      BARF;
      af[0][0] = RD_A(c, 4, 0); af[0][1] = RD_A(c, 4, 1);
      af[1][0] = RD_A(c, 5, 0); af[1][1] = RD_A(c, 5, 1);
      stageH(c, 1, W, n0, kb2, 0);
      __builtin_amdgcn_s_setprio(1);
      #pragma unroll
      for (int m = 0; m < 2; m++)
        #pragma unroll
        for (int n = 0; n < 4; n++){
          acc[m + 4][n] = MFMA(af[m][0], bq[n][0], acc[m + 4][n]);
          acc[m + 4][n] = MFMA(af[m][1], bq[n][1], acc[m + 4][n]);
        }
      __builtin_amdgcn_s_setprio(0);
      BARF;
      af[0][0] = RD_A(c, 6, 0); af[0][1] = RD_A(c, 6, 1);
      af[1][0] = RD_A(c, 7, 0); af[1][1] = RD_A(c, 7, 1);
      stageH(c, 1, W, n0, kb2, 1);
      __builtin_amdgcn_s_setprio(1);
      #pragma unroll
      for (int m = 0; m < 2; m++)
        #pragma unroll
        for (int n = 0; n < 4; n++){
          acc[m + 6][n] = MFMA(af[m][0], bq[n][0], acc[m + 6][n]);
          acc[m + 6][n] = MFMA(af[m][1], bq[n][1], acc[m + 6][n]);
        }
      __builtin_amdgcn_s_setprio(0);
      asm volatile("s_waitcnt vmcnt(4)" ::: "memory");
      BARF;
    }
  }
  #undef RD_A
  #undef RD_B

  asm volatile("s_waitcnt vmcnt(0)" ::: "memory");
  BARF;

  const float* bp = (n0 < p.nsplit) ? p.b1 : (p.b2 - p.nsplit);
  float bn[4];
  #pragma unroll
  for (int n = 0; n < 4; n++) bn[n] = bp[n0 + (wc << 6) + (n << 4) + ln15];

  if constexpr (RES){
    float* cw = &sm.cep[wid][0];
    const int rr = lane >> 3, cb8 = (lane & 7) << 3;
    #pragma unroll
    for (int m = 0; m < 8; m++){
      #pragma unroll
      for (int n = 0; n < 4; n++)
        #pragma unroll
        for (int r = 0; r < 4; r++)
          cw[((hi << 2) + r) * 66 + (n << 4) + ln15] = acc[m][n][r] + bn[n];
      #pragma unroll
      for (int j = 0; j < 2; j++){
        const int row = (j << 3) + rr;
        const size_t gr = (size_t)(m0 + (wr << 7) + (m << 4) + row);
        const size_t gidx = gr * LDC + n0 + (wc << 6) + cb8;
        const size_t ridx = gr * HIDD + n0 + (wc << 6) + cb8;
        const uint4 rv = *(const uint4*)&residb[ridx];
        const u32 rr4[4] = {rv.x, rv.y, rv.z, rv.w};
        float4 o0, o1;
        o0.x = cw[row * 66 + cb8 + 0] + bf2f((u16)(rr4[0] & 0xffff));
        o0.y = cw[row * 66 + cb8 + 1] + bf2f((u16)(rr4[0] >> 16));
        o0.z = cw[row * 66 + cb8 + 2] + bf2f((u16)(rr4[1] & 0xffff));
        o0.w = cw[row * 66 + cb8 + 3] + bf2f((u16)(rr4[1] >> 16));
        o1.x = cw[row * 66 + cb8 + 4] + bf2f((u16)(rr4[2] & 0xffff));
        o1.y = cw[row * 66 + cb8 + 5] + bf2f((u16)(rr4[2] >> 16));
        o1.z = cw[row * 66 + cb8 + 6] + bf2f((u16)(rr4[3] & 0xffff));
        o1.w = cw[row * 66 + cb8 + 7] + bf2f((u16)(rr4[3] >> 16));
        *(float4*)&outf[gidx]     = o0;
        *(float4*)&outf[gidx + 4] = o1;
      }
    }
  } else if (p.voutT != nullptr && n0 >= p.nsplit){
    // V half: store transposed to vT[((b*16+h)*64 + d)*SQ + s], 64B burst per lane
    float* cw = &sm.cep2[wid][0];                 // [32][66]
    const int e0 = n0 - p.nsplit + (wc << 6);
    const int hh = e0 >> 6;
    u16* vt = p.voutT;
    #pragma unroll
    for (int mp = 0; mp < 4; mp++){
      #pragma unroll
      for (int mh = 0; mh < 2; mh++){
        const int m = (mp << 1) + mh;
        #pragma unroll
        for (int n = 0; n < 4; n++)
          #pragma unroll
          for (int r = 0; r < 4; r++)
            cw[((mh << 4) + (hi << 2) + r) * 66 + (n << 4) + ln15] = acc[m][n][r] + bn[n];
      }
      const int rg0 = m0 + (wr << 7) + (mp << 5);
      const int bb = rg0 >> 12, s0 = rg0 & 4095;
      u16* dst = vt + (((size_t)(bb << 4) + hh) * 64 + lane) * SQ + s0;
      #pragma unroll
      for (int j = 0; j < 4; j++){
        u32 ro[4];
        #pragma unroll
        for (int q = 0; q < 4; q++){
          float v0 = cw[((j << 3) + 2 * q    ) * 66 + lane];
          float v1 = cw[((j << 3) + 2 * q + 1) * 66 + lane];
          ro[q] = (u32)f2bf(v0) | ((u32)f2bf(v1) << 16);
        }
        uint4 o; o.x = ro[0]; o.y = ro[1]; o.z = ro[2]; o.w = ro[3];
        *(uint4*)&dst[j << 3] = o;
      }
    }
  } else {
    float* cw = &sm.cep[wid][0];
    const int rr = lane >> 3, cb8 = (lane & 7) << 3;
    u16* outb = p.outb;
    if (p.cq != nullptr){
      // Q path: LN-linearized correction, then bf16 row-major store
      float cqn[4], dqn[4];
      #pragma unroll
      for (int n = 0; n < 4; n++){
        const int col = n0 + (wc << 6) + (n << 4) + ln15;
        cqn[n] = p.cq[col]; dqn[n] = p.dq[col];
      }
      #pragma unroll
      for (int m = 0; m < 8; m++){
        #pragma unroll
        for (int r = 0; r < 4; r++){
          const int grow = m0 + (wr << 7) + (m << 4) + (hi << 2) + r;
          const float mu = p.mur[grow], rs = p.rsd[grow];
          #pragma unroll
          for (int n = 0; n < 4; n++)
            cw[((hi << 2) + r) * 66 + (n << 4) + ln15] = rs * acc[m][n][r] - mu * cqn[n] + dqn[n];
        }
        #pragma unroll
        for (int j = 0; j < 2; j++){
          const int row = (j << 3) + rr;
          u32 ro[4];
          #pragma unroll
          for (int pq = 0; pq < 4; pq++){
            float v0 = cw[row * 66 + cb8 + 2 * pq];
            float v1 = cw[row * 66 + cb8 + 2 * pq + 1];
            ro[pq] = (u32)f2bf(v0) | ((u32)f2bf(v1) << 16);
          }
          uint4 o; o.x = ro[0]; o.y = ro[1]; o.z = ro[2]; o.w = ro[3];
          *(uint4*)&outb[(size_t)(m0 + (wr << 7) + (m << 4) + row) * LDC
                         + n0 + (wc << 6) + cb8] = o;
        }
      }
    } else {
      #pragma unroll
      for (int m = 0; m < 8; m++){
        #pragma unroll
        for (int n = 0; n < 4; n++)
          #pragma unroll
          for (int r = 0; r < 4; r++)
            cw[((hi << 2) + r) * 66 + (n << 4) + ln15] = acc[m][n][r] + bn[n];
        #pragma unroll
        for (int j = 0; j < 2; j++){
          const int row = (j << 3) + rr;
          u32 ro[4];
          #pragma unroll
          for (int pq = 0; pq < 4; pq++){
            float v0 = cw[row * 66 + cb8 + 2 * pq];
            float v1 = cw[row * 66 + cb8 + 2 * pq + 1];
            ro[pq] = (u32)f2bf(v0) | ((u32)f2bf(v1) << 16);
          }
          uint4 o; o.x = ro[0]; o.y = ro[1]; o.z = ro[2]; o.w = ro[3];
          *(uint4*)&outb[(size_t)(m0 + (wr << 7) + (m << 4) + row) * LDC
                         + n0 + (wc << 6) + cb8] = o;
        }
      }
    }
  }
  #undef BARF
}

// ---------------- transpose K: kb [B,S,1024] -> ekT [B,H,64,S] with elu+L2norm ----------------
__global__ __launch_bounds__(256) void k_transposeK(const u16* __restrict__ kb,
                                                    u16* __restrict__ ekT){
  __shared__ float tile[64][65];
  __shared__ float pr[64][4];
  __shared__ float rn[64];
  const int sb = blockIdx.x << 6, h = blockIdx.y, b = blockIdx.z;
  const int t = threadIdx.x;
  {
    const int tok = t >> 2, q = t & 3;
    const u16* src = kb + (size_t)(b * SQ + sb + tok) * 1024 + (h << 6) + (q << 4);
    uint4 u0 = *(const uint4*)src;
    uint4 u1 = *(const uint4*)(src + 8);
    u32 uu[8] = {u0.x, u0.y, u0.z, u0.w, u1.x, u1.y, u1.z, u1.w};
    float ss = 0.f;
    #pragma unroll
    for (int i = 0; i < 8; i++){
      float f0 = bf2f((u16)(uu[i] & 0xffff));
      float f1 = bf2f((u16)(uu[i] >> 16));
      f0 = f0 > 0.f ? f0 : expm1f(f0);
      f1 = f1 > 0.f ? f1 : expm1f(f1);
      ss += f0 * f0 + f1 * f1;
      tile[tok][(q << 4) + 2*i]     = f0;
      tile[tok][(q << 4) + 2*i + 1] = f1;
    }
    pr[tok][q] = ss;
  }
  __syncthreads();
  if (t < 64) rn[t] = rsqrtf(pr[t][0] + pr[t][1] + pr[t][2] + pr[t][3]);
  __syncthreads();
  const int d = t >> 2, sq2 = (t & 3) << 4;
  u16* dst = ekT + ((size_t)(b * NHQ + h) * 64 + d) * SQ + sb + sq2;
  u32 ro[8];
  #pragma unroll
  for (int i = 0; i < 8; i++){
    float v0 = tile[sq2 + 2*i][d]     * rn[sq2 + 2*i];
    float v1 = tile[sq2 + 2*i + 1][d] * rn[sq2 + 2*i + 1];
    ro[i] = (u32)f2bf(v0) | ((u32)f2bf(v1) << 16);
  }
  uint4 o0; o0.x = ro[0]; o0.y = ro[1]; o0.z = ro[2]; o0.w = ro[3];
  uint4 o1; o1.x = ro[4]; o1.y = ro[5]; o1.z = ro[6]; o1.w = ro[7];
  *(uint4*)dst = o0;
  *(uint4*)(dst + 8) = o1;
}

// ---------------- kv split-K: per (b,h,half) partial[e][d] = sum_{s in half} v[s][e] ek[s][d] ----------------
__global__ __launch_bounds__(256) void k_kv(const u16* __restrict__ vT, const u16* __restrict__ ekT,
                                            float* __restrict__ kvP){
  const int half = blockIdx.x & 1, bh = blockIdx.x >> 1;
  const u16* Av = vT  + (size_t)bh * 64 * SQ;
  const u16* Bk = ekT + (size_t)bh * 64 * SQ;
  const int lane = threadIdx.x & 63, wid = threadIdx.x >> 6;
  const int ln15 = lane & 15, hi = lane >> 4;
  f32x4 acc[4][4] = {};
  const int kb = (half << 11) + (wid << 9);
  for (int ks = 0; ks < 16; ++ks){
    const int k0 = kb + (ks << 5) + (hi << 3);
    bf16x8 af[4], bfr[4];
    #pragma unroll
    for (int m = 0; m < 4; m++) af[m]  = *(const bf16x8*)(Av + (size_t)((m << 4) + ln15) * SQ + k0);
    #pragma unroll
    for (int n = 0; n < 4; n++) bfr[n] = *(const bf16x8*)(Bk + (size_t)((n << 4) + ln15) * SQ + k0);
    #pragma unroll
    for (int m = 0; m < 4; m++)
      #pragma unroll
      for (int n = 0; n < 4; n++)
        acc[m][n] = MFMA(af[m], bfr[n], acc[m][n]);
  }
  __shared__ float red[64][64];
  for (int w = 0; w < 4; ++w){
    if (wid == w){
      #pragma unroll
      for (int m = 0; m < 4; m++)
        #pragma unroll
        for (int n = 0; n < 4; n++)
          #pragma unroll
          for (int r = 0; r < 4; r++){
            int row = (m << 4) + (hi << 2) + r;
            int col = (n << 4) + ln15;
            if (w == 0) red[row][col] = acc[m][n][r];
            else        red[row][col] += acc[m][n][r];
          }
    }
    __syncthreads();
  }
  float* dst = kvP + (size_t)blockIdx.x * 4096;
  const int tt = threadIdx.x;
  #pragma unroll
  for (int i = 0; i < 16; i++){
    int idx = tt * 16 + i;
    dst[idx] = red[idx >> 6][idx & 63];
  }
}

// ---------------- kvr: kvT = bf16((p0 + p1) * 0.125) ----------------
__global__ __launch_bounds__(256) void k_kvr(const float* __restrict__ kvP,
                                             u16* __restrict__ kvT){
  const int bh = blockIdx.x, t = threadIdx.x;
  const float* p0 = kvP + (size_t)(bh << 1) * 4096;
  const float* p1 = p0 + 4096;
  u16* dst = kvT + (size_t)bh * 4096;
  #pragma unroll
  for (int i = 0; i < 2; i++){
    const int idx = (i << 11) + (t << 3);
    const float4 a0 = *(const float4*)&p0[idx];
    const float4 a1 = *(const float4*)&p0[idx + 4];
    const float4 b0 = *(const float4*)&p1[idx];
    const float4 b1 = *(const float4*)&p1[idx + 4];
    u32 ro[4];
    ro[0] = (u32)f2bf((a0.x + b0.x) * 0.125f) | ((u32)f2bf((a0.y + b0.y) * 0.125f) << 16);
    ro[1] = (u32)f2bf((a0.z + b0.z) * 0.125f) | ((u32)f2bf((a0.w + b0.w) * 0.125f) << 16);
    ro[2] = (u32)f2bf((a1.x + b1.x) * 0.125f) | ((u32)f2bf((a1.y + b1.y) * 0.125f) << 16);
    ro[3] = (u32)f2bf((a1.z + b1.z) * 0.125f) | ((u32)f2bf((a1.w + b1.w) * 0.125f) << 16);
    uint4 o; o.x = ro[0]; o.y = ro[1]; o.z = ro[2]; o.w = ro[3];
    *(uint4*)&dst[idx] = o;
  }
}

// ---------------- ctx (+ fused elu/L2norm on q): ctx[s][e] = sum_d eq[s][d] * kv[d][e] ----------------
__global__ __launch_bounds__(256) void k_ctx(const u16* __restrict__ q, const u16* __restrict__ kvT,
                                             u16* __restrict__ ctx){
  __shared__ u16 Alds[1024 * 8];
  __shared__ u16 Blds[512 * 8];
  __shared__ float prn[128][2];
  const int sb = blockIdx.x << 7;
  const int h = blockIdx.y, b = blockIdx.z;
  const int bh = (b << 4) + h;
  const int t = threadIdx.x, lane = t & 63, wid = t >> 6;
  const int ln15 = lane & 15, hi = lane >> 4;
  {
    uint4 va[4]; uint4 vb[2];
    #pragma unroll
    for (int i = 0; i < 4; i++){
      int c = (wid << 6) + (i << 8) + lane;
      int g = c >> 7, row = c & 127;
      va[i] = *(const uint4*)(q + (size_t)(b * SQ + sb + row) * HIDD + (h << 6) + g * 8);
    }
    #pragma unroll
    for (int i = 0; i < 2; i++){
      int c = (wid << 6) + (i << 8) + lane;
      int g = c >> 6, row = c & 63;
      vb[i] = *(const uint4*)(kvT + (size_t)bh * 4096 + (row << 6) + g * 8);
    }
    #pragma unroll
    for (int i = 0; i < 4; i++)
      *(uint4*)&Alds[((wid << 6) + (i << 8) + lane) * 8] = va[i];
    #pragma unroll
    for (int i = 0; i < 2; i++)
      *(uint4*)&Blds[((wid << 6) + (i << 8) + lane) * 8] = vb[i];
  }
  __syncthreads();
  {
    const int row = t & 127, half = t >> 7;
    float vals[4][8]; float ss = 0.f;
    #pragma unroll
    for (int g4 = 0; g4 < 4; g4++){
      const int g = (half << 2) + g4;
      uint4 u = *(const uint4*)&Alds[((g << 7) + row) * 8];
      u32 uu[4] = {u.x, u.y, u.z, u.w};
      #pragma unroll
      for (int i = 0; i < 4; i++){
        float f0 = bf2f((u16)(uu[i] & 0xffff));
        float f1 = bf2f((u16)(uu[i] >> 16));
        f0 = f0 > 0.f ? f0 : expm1f(f0);
        f1 = f1 > 0.f ? f1 : expm1f(f1);
        vals[g4][2*i] = f0; vals[g4][2*i+1] = f1;
        ss += f0 * f0 + f1 * f1;
      }
    }
    prn[row][half] = ss;
    __syncthreads();
    const float rn = rsqrtf(prn[row][0] + prn[row][1]);
    #pragma unroll
    for (int g4 = 0; g4 < 4; g4++){
      const int g = (half << 2) + g4;
      u32 ro[4];
      #pragma unroll
      for (int i = 0; i < 4; i++)
        ro[i] = (u32)f2bf(vals[g4][2*i] * rn) | ((u32)f2bf(vals[g4][2*i+1] * rn) << 16);
      uint4 o; o.x = ro[0]; o.y = ro[1]; o.z = ro[2]; o.w = ro[3];
      *(uint4*)&Alds[((g << 7) + row) * 8] = o;
    }
  }
  __syncthreads();
  f32x4 acc[2][4] = {};
  #pragma unroll
  for (int k2 = 0; k2 < 2; k2++){
    const int g = (k2 << 2) + hi;
    bf16x8 af[2], bfr[4];
    #pragma unroll
    for (int m = 0; m < 2; m++) af[m]  = *(const bf16x8*)&Alds[((g << 7) + (wid << 5) + (m << 4) + ln15) * 8];
    #pragma unroll
    for (int n = 0; n < 4; n++) bfr[n] = *(const bf16x8*)&Blds[((g << 6) + (n << 4) + ln15) * 8];
    #pragma unroll
    for (int m = 0; m < 2; m++)
      #pragma unroll
      for (int n = 0; n < 4; n++)
        acc[m][n] = MFMA(af[m], bfr[n], acc[m][n]);
  }
  #pragma unroll
  for (int m = 0; m < 2; m++)
    #pragma unroll
    for (int n = 0; n < 4; n++)
      #pragma unroll
      for (int r = 0; r < 4; r++){
        int srow = sb + (wid << 5) + (m << 4) + (hi << 2) + r;
        int col  = (n << 4) + ln15;
        ctx[(size_t)(b * SQ + srow) * HIDD + (h << 6) + col] = f2bf(acc[m][n][r]);
      }
}

extern "C" void kernel_launch(void* const* d_in, const int* in_sizes, int n_in,
                              void* d_out, int out_size, void* d_ws, size_t ws_size,
                              hipStream_t stream){
  const float* x   = (const float*)d_in[0];
  const float* lng = (const float*)d_in[2];
  const float* lnb = (const float*)d_in[3];
  const float* Wq  = (const float*)d_in[4];
  const float* bq  = (const float*)d_in[5];
  const float* Wk  = (const float*)d_in[6];
  const float* bk  = (const float*)d_in[7];
  const float* Wv  = (const float*)d_in[8];
  const float* bv  = (const float*)d_in[9];
  const float* Wo  = (const float*)d_in[10];
  const float* bo  = (const float*)d_in[11];
  float* out = (float*)d_out;

  char* w = (char*)d_ws;
  const size_t MB = 1ull << 20;
  u16* wqb  = (u16*)(w + 0   * MB);   // 2 MiB: Wq' = gamma*Wq (bf16)
  u16* wkvb = (u16*)(w + 2   * MB);   // 4 MiB: [Wk; Wv] stacked [2048][1024]
  u16* wob  = (u16*)(w + 6   * MB);   // 2 MiB
  u16* xbf  = (u16*)(w + 8   * MB);   // 64 MiB (live through out-GEMM: bf16 residual)
  u16* xnbf = (u16*)(w + 72  * MB);   // 64 MiB (ekT scratch)
  u16* qb   = (u16*)(w + 136 * MB);   // 64 MiB (raw q; elu+norm fused into k_ctx)
  u16* kb   = (u16*)(w + 200 * MB);   // 64 MiB (raw k, row-major)
  u16* vT   = (u16*)(w + 264 * MB);   // 64 MiB (v transposed [B,H,64,S], direct from GEMM)
  u16* kvT  = (u16*)(w + 328 * MB);   // 1 MiB
  float* murstd = (float*)(w + 330 * MB);  // 128 KiB
  float* rstdv  = (float*)(w + 331 * MB);  // 128 KiB
  float* cqv    = (float*)(w + 332 * MB);  // 4 KiB
  float* dqv    = (float*)(w + 333 * MB);  // 4 KiB
  float* kvP    = (float*)(w + 336 * MB);  // 4 MiB f32 split-K partials
  // aliases (stream-ordered lifetimes)
  u16* ekT = xnbf;
  u16* ctx = kb;    // kb dead after k_transposeK

  // merged head: LN (32768 blocks) || weight casts (3072) || Wq' prep (1024)
  k_head<<<TOKN + 4096, 256, 0, stream>>>(x, xbf, murstd, rstdv,
                                          Wk, Wv, Wo, Wq, lng, lnb, bq,
                                          wkvb, wob, wqb, cqv, dqv);

  // merged Q + KV GEMM (2-phase): Q blocks [0,512) with A=xbf + LN-linearized epilogue;
  // KV blocks [512,1536): K half -> kb row-major; V half -> vT transposed
  GP pq  = { xbf, wqb,  bq, bq, 1 << 30, 2, 1024, 512,  qb, nullptr, cqv, dqv, murstd, rstdv };
  GP pkv = { xbf, wkvb, bk, bv, 1024,    3, 1024, 1024, kb, vT,      nullptr, nullptr, nullptr, nullptr };
  k_gemm256<0, 0><<<1536, 512, 0, stream>>>(pq, pkv, 512, nullptr, nullptr);

  k_transposeK<<<dim3(64, 16, 8), 256, 0, stream>>>(kb, ekT);
  k_kv<<<256, 256, 0, stream>>>(vT, ekT, kvP);
  k_kvr<<<128, 256, 0, stream>>>(kvP, kvT);
  k_ctx<<<dim3(32, 16, 8), 256, 0, stream>>>(qb, kvT, ctx);

  // out GEMM (4-phase): bf16 residual from xbf + fp32 out
  GP po = { ctx, wob, bo, bo, 1 << 30, 2, 1024, 512, nullptr, nullptr,
            nullptr, nullptr, nullptr, nullptr };
  k_gemm256<1, 1><<<512, 512, 0, stream>>>(po, po, 512, xbf, out);

  (void)in_sizes; (void)n_in; (void)out_size; (void)ws_size;
}